// Round 4
// baseline (2991.744 us; speedup 1.0000x reference)
//
#include <hip/hip_runtime.h>

// ---------------------------------------------------------------------------
// AttentionDecoder: B=64 T=32 S=64 H=1024 V=32000
// R4: persistent recurrence, cached-normal bulk loads + rotated buffers.
//  - Inter-block safety: producers ATOMIC-store (coherent point); consumers
//    NORMAL-load buffers they never touched before (per-step rotation) ->
//    clean L2 miss -> fresh data. Weights/encT/encL/embi always cached.
//  - encL = enc @ l2a^T precomputed: ctx_{t+1} = tanh(attn@encL + h@l2b^T)
//    eliminates cat buffer + 4th phase. 3 barriers/step.
//  - Ph1(192 blk): gi=ctx@wih2^T, gh=h@whh^T (split-K 2x, 64x64 tiles)
//    Ph2(64 blk): GRU (h_prev in regs) + scores(encT) + softmax + attnctx
//    Ph3(16 blk): hl2=h@l2b^T full-K + tanh finalize -> dctx[t+1]
//  - Logits GEMM + log-softmax unchanged. wout bf16 conversion moved after
//    k_rec so its buffer overlays dead prep arena.
// ---------------------------------------------------------------------------

#define B_ 64
#define T_ 32
#define S_ 64
#define H_ 1024
#define V_ 32000
#define NB_ 192

#define HID_OFF 65536000L
#define ATT_OFF 65601536L
#define CTF_OFF 65732608L

typedef __attribute__((ext_vector_type(8))) short bf16x8;
typedef __attribute__((ext_vector_type(4))) float f32x4;
typedef __attribute__((ext_vector_type(4))) unsigned int u32x4;
typedef unsigned short u16;
typedef unsigned long long u64;

__device__ __forceinline__ u16 f2bf(float v) {
  unsigned int u = __float_as_uint(v);
  unsigned int r = (u + 0x7fffu + ((u >> 16) & 1u)) >> 16;  // RNE
  return (u16)r;
}
__device__ __forceinline__ float bf2f(u16 h) {
  return __uint_as_float(((unsigned int)h) << 16);
}
__device__ __forceinline__ void split2(float v, u16* hi, u16* lo) {
  u16 h = f2bf(v);
  *hi = h;
  *lo = f2bf(v - bf2f(h));
}

// ---- coherent-path (agent-scope relaxed atomic) helpers ----
__device__ __forceinline__ u64 aload_u64(const void* p) {
  return __hip_atomic_load((const u64*)p, __ATOMIC_RELAXED, __HIP_MEMORY_SCOPE_AGENT);
}
__device__ __forceinline__ void astore_u64(void* p, u64 v) {
  __hip_atomic_store((u64*)p, v, __ATOMIC_RELAXED, __HIP_MEMORY_SCOPE_AGENT);
}
__device__ __forceinline__ void astore_f32(float* p, float v) {
  __hip_atomic_store((unsigned*)p, __float_as_uint(v), __ATOMIC_RELAXED,
                     __HIP_MEMORY_SCOPE_AGENT);
}
__device__ __forceinline__ void aload4f(const float* p, float* d) {
  u64 a = aload_u64(p), b = aload_u64(p + 2);
  d[0] = __uint_as_float((unsigned)a);
  d[1] = __uint_as_float((unsigned)(a >> 32));
  d[2] = __uint_as_float((unsigned)b);
  d[3] = __uint_as_float((unsigned)(b >> 32));
}

// ---------------- conversion / prep kernels ----------------

__global__ void k_split(const float* __restrict__ src, u16* __restrict__ hi,
                        u16* __restrict__ lo, int n) {
  int i = blockIdx.x * blockDim.x + threadIdx.x;
  int stride = gridDim.x * blockDim.x;
  for (; i < n; i += stride) split2(src[i], &hi[i], &lo[i]);
}

__global__ void k_tobf(const float* __restrict__ src, u16* __restrict__ dst, int n) {
  int i = blockIdx.x * blockDim.x + threadIdx.x;
  int stride = gridDim.x * blockDim.x;
  for (; i < n; i += stride) dst[i] = f2bf(src[i]);
}

// l1 (H,H) row-major [i][k] -> l1T hi/lo [k][i]
__global__ void k_l1t(const float* __restrict__ l1, u16* __restrict__ hi,
                      u16* __restrict__ lo) {
  __shared__ float tile[64][65];
  int it = blockIdx.x & 15, kt = blockIdx.x >> 4;
  for (int q = 0; q < 16; ++q) {
    int idx = q * 256 + threadIdx.x;
    int r = idx >> 6, c = idx & 63;
    tile[r][c] = l1[(long)(it * 64 + r) * H_ + kt * 64 + c];
  }
  __syncthreads();
  for (int q = 0; q < 16; ++q) {
    int idx = q * 256 + threadIdx.x;
    int r = idx >> 6, c = idx & 63;
    long o = (long)(kt * 64 + r) * H_ + it * 64 + c;
    split2(tile[c][r], &hi[o], &lo[o]);
  }
}

// gather embeddings: embx[t][b][k] hi/lo
__global__ void k_embx(const int* __restrict__ inp, const float* __restrict__ emb,
                       u16* __restrict__ hi, u16* __restrict__ lo) {
  int bt = blockIdx.x;
  int b = bt >> 5, t = bt & 31;
  int id = inp[b * T_ + t];
  const float* src = emb + (long)id * H_;
  long base = (long)(t * B_ + b) * H_;
  for (int k = threadIdx.x; k < H_; k += 256) split2(src[k], &hi[base + k], &lo[base + k]);
}

// h0 -> hh_r/hl_r slot 0
__global__ void k_h0(const float* __restrict__ mem, u16* __restrict__ hh,
                     u16* __restrict__ hl) {
  int i = blockIdx.x * 256 + threadIdx.x;  // 65536
  float v = mem[i];
  split2(v, &hh[i], &hl[i]);
}

__global__ void k_guard(float* out, float v) {
  if (blockIdx.x == 0 && threadIdx.x == 0) out[0] = v;
}

// ---------------- 128x128 tile GEMM (BK=32), optional split-bf16 ----------------
template <int SPLIT, int OMODE>
__launch_bounds__(256)
__global__ void k_gemm128(const u16* __restrict__ Ah, const u16* __restrict__ Al,
                          const u16* __restrict__ Bh, const u16* __restrict__ Bl,
                          float* __restrict__ C, const float* __restrict__ bias,
                          int Mtiles, int Ntiles, int K, int Arow, int Brow, int Crow) {
  (void)Ntiles;
  int bx = blockIdx.x;
  int mt = bx % Mtiles, nt = bx / Mtiles;
  int m0 = mt * 128, n0 = nt * 128;

  __shared__ __attribute__((aligned(16))) u16 lds[(SPLIT ? 4 : 2) * 4096];
  char* L = (char*)lds;
  const int tid = threadIdx.x;
  const int lane = tid & 63, wid = tid >> 6;
  const int wm = wid & 1, wn = wid >> 1;
  const int l15 = lane & 15, kq = lane >> 4;

  f32x4 acc[4][4];
  const f32x4 z4 = {0.f, 0.f, 0.f, 0.f};
#pragma unroll
  for (int i = 0; i < 4; ++i)
#pragma unroll
    for (int j = 0; j < 4; ++j) acc[i][j] = z4;

  const int ksteps = K >> 5;
  for (int kt = 0; kt < ksteps; ++kt) {
    __syncthreads();
#pragma unroll
    for (int h2 = 0; h2 < 2; ++h2) {
      int r = (tid >> 2) + (h2 << 6);
      int slot = tid & 3;
      int so = ((slot ^ (r & 3)) << 4);
      long ga = (long)(m0 + r) * Arow + (kt << 5) + (slot << 3);
      long gb = (long)(n0 + r) * Brow + (kt << 5) + (slot << 3);
      *(u32x4*)(L + r * 64 + so) = *(const u32x4*)(Ah + ga);
      *(u32x4*)(L + 8192 + r * 64 + so) = *(const u32x4*)(Bh + gb);
      if (SPLIT) {
        *(u32x4*)(L + 16384 + r * 64 + so) = *(const u32x4*)(Al + ga);
        *(u32x4*)(L + 24576 + r * 64 + so) = *(const u32x4*)(Bl + gb);
      }
    }
    __syncthreads();
    bf16x8 aH[4], bH[4], aL[4], bL[4];
#pragma unroll
    for (int mi = 0; mi < 4; ++mi) {
      int r = (wm << 6) + (mi << 4) + l15;
      int off = r * 64 + ((kq ^ (r & 3)) << 4);
      aH[mi] = *(const bf16x8*)(L + off);
      if (SPLIT) aL[mi] = *(const bf16x8*)(L + 16384 + off);
    }
#pragma unroll
    for (int ni = 0; ni < 4; ++ni) {
      int c = (wn << 6) + (ni << 4) + l15;
      int off = c * 64 + ((kq ^ (c & 3)) << 4);
      bH[ni] = *(const bf16x8*)(L + 8192 + off);
      if (SPLIT) bL[ni] = *(const bf16x8*)(L + 24576 + off);
    }
#pragma unroll
    for (int mi = 0; mi < 4; ++mi)
#pragma unroll
      for (int ni = 0; ni < 4; ++ni) {
        acc[mi][ni] = __builtin_amdgcn_mfma_f32_16x16x32_bf16(aH[mi], bH[ni], acc[mi][ni], 0, 0, 0);
        if (SPLIT) {
          acc[mi][ni] = __builtin_amdgcn_mfma_f32_16x16x32_bf16(aL[mi], bH[ni], acc[mi][ni], 0, 0, 0);
          acc[mi][ni] = __builtin_amdgcn_mfma_f32_16x16x32_bf16(aH[mi], bL[ni], acc[mi][ni], 0, 0, 0);
        }
      }
  }
#pragma unroll
  for (int mi = 0; mi < 4; ++mi)
#pragma unroll
    for (int ni = 0; ni < 4; ++ni)
#pragma unroll
      for (int e = 0; e < 4; ++e) {
        int r = (wm << 6) + (mi << 4) + (kq << 2) + e;
        int c = (wn << 6) + (ni << 4) + l15;
        int gm = m0 + r, gn = n0 + c;
        float v = acc[mi][ni][e];
        if (OMODE == 0) {
          C[(long)gm * Crow + gn] = v;
        } else {
          v += bias[gn];
          C[((long)(gm & 63) * T_ + (gm >> 6)) * V_ + gn] = v;
        }
      }
}

// ---------------- 64x64 split-bf16 GEMM tile (device fn, normal loads) -----
__device__ __forceinline__ void gemm64_tile(const u16* __restrict__ Ah,
                                            const u16* __restrict__ Al, int Ar,
                                            const u16* __restrict__ Bh,
                                            const u16* __restrict__ Bl, int Br,
                                            int kiters, char* L, f32x4 (&acc)[2][2]) {
  const int tid = threadIdx.x;
  const int lane = tid & 63, wid = tid >> 6;
  const int wm = wid & 1, wn = wid >> 1;
  const int l15 = lane & 15, kq = lane >> 4;
  const int r = tid >> 2, slot = tid & 3;
  const int so = ((slot ^ (r & 3)) << 4);

  u32x4 rAh, rBh, rAl, rBl;
  {
    long ga = (long)r * Ar + (slot << 3);
    long gb = (long)r * Br + (slot << 3);
    rAh = *(const u32x4*)(Ah + ga);
    rAl = *(const u32x4*)(Al + ga);
    rBh = *(const u32x4*)(Bh + gb);
    rBl = *(const u32x4*)(Bl + gb);
  }
  for (int kt = 0; kt < kiters; ++kt) {
    __syncthreads();
    *(u32x4*)(L + r * 64 + so) = rAh;
    *(u32x4*)(L + 4096 + r * 64 + so) = rBh;
    *(u32x4*)(L + 8192 + r * 64 + so) = rAl;
    *(u32x4*)(L + 12288 + r * 64 + so) = rBl;
    __syncthreads();
    if (kt + 1 < kiters) {
      long ga = (long)r * Ar + ((kt + 1) << 5) + (slot << 3);
      long gb = (long)r * Br + ((kt + 1) << 5) + (slot << 3);
      rAh = *(const u32x4*)(Ah + ga);
      rAl = *(const u32x4*)(Al + ga);
      rBh = *(const u32x4*)(Bh + gb);
      rBl = *(const u32x4*)(Bl + gb);
    }
    bf16x8 aH[2], aL[2], bH[2], bL[2];
#pragma unroll
    for (int mi = 0; mi < 2; ++mi) {
      int rr = (wm << 5) + (mi << 4) + l15;
      int off = rr * 64 + ((kq ^ (rr & 3)) << 4);
      aH[mi] = *(const bf16x8*)(L + off);
      aL[mi] = *(const bf16x8*)(L + 8192 + off);
    }
#pragma unroll
    for (int ni = 0; ni < 2; ++ni) {
      int c = (wn << 5) + (ni << 4) + l15;
      int off = c * 64 + ((kq ^ (c & 3)) << 4);
      bH[ni] = *(const bf16x8*)(L + 4096 + off);
      bL[ni] = *(const bf16x8*)(L + 12288 + off);
    }
#pragma unroll
    for (int mi = 0; mi < 2; ++mi)
#pragma unroll
      for (int ni = 0; ni < 2; ++ni) {
        acc[mi][ni] = __builtin_amdgcn_mfma_f32_16x16x32_bf16(aH[mi], bH[ni], acc[mi][ni], 0, 0, 0);
        acc[mi][ni] = __builtin_amdgcn_mfma_f32_16x16x32_bf16(aL[mi], bH[ni], acc[mi][ni], 0, 0, 0);
        acc[mi][ni] = __builtin_amdgcn_mfma_f32_16x16x32_bf16(aH[mi], bL[ni], acc[mi][ni], 0, 0, 0);
      }
  }
}

// ---------------- grid barrier: release flag + distributed relaxed poll ----
__device__ __forceinline__ void gridbar(unsigned* flags, unsigned seq) {
  __syncthreads();
  if (threadIdx.x == 0)
    __hip_atomic_store(flags + blockIdx.x * 16, seq, __ATOMIC_RELEASE,
                       __HIP_MEMORY_SCOPE_AGENT);
  if (threadIdx.x < 64) {
    int l = threadIdx.x;
    for (;;) {
      unsigned a = __hip_atomic_load(flags + l * 16, __ATOMIC_RELAXED, __HIP_MEMORY_SCOPE_AGENT);
      unsigned b = __hip_atomic_load(flags + (l + 64) * 16, __ATOMIC_RELAXED, __HIP_MEMORY_SCOPE_AGENT);
      unsigned c = __hip_atomic_load(flags + (l + 128) * 16, __ATOMIC_RELAXED, __HIP_MEMORY_SCOPE_AGENT);
      if (__all((a >= seq) & (b >= seq) & (c >= seq))) break;
      __builtin_amdgcn_s_sleep(1);
    }
  }
  __syncthreads();
}

// ---------------- persistent recurrence kernel ----------------
__launch_bounds__(256)
__global__ void k_rec(const float* __restrict__ embi,
                      u16* __restrict__ dctx_h, u16* __restrict__ dctx_l,
                      u16* __restrict__ hh_r, u16* __restrict__ hl_r,
                      const float* __restrict__ memory,
                      const u16* __restrict__ wih_h, const u16* __restrict__ wih_l,
                      const u16* __restrict__ whh_h, const u16* __restrict__ whh_l,
                      const u16* __restrict__ l2_h, const u16* __restrict__ l2_l,
                      float* __restrict__ gip, float* __restrict__ ghp,
                      float* __restrict__ attnctx,
                      const float* __restrict__ encT, const float* __restrict__ encL,
                      const int* __restrict__ xs_len,
                      const float* __restrict__ bih, const float* __restrict__ bhh,
                      float* __restrict__ dout, unsigned* flags) {
  __shared__ __attribute__((aligned(16))) char L[32768];
  const int bx = blockIdx.x;
  const int tid = threadIdx.x;
  const int lane = tid & 63, wid = tid >> 6;
  const int wm = wid & 1, wn = wid >> 1;
  const int l15 = lane & 15, kq = lane >> 4;
  const f32x4 z4 = {0.f, 0.f, 0.f, 0.f};
  unsigned seq = 1;

  // h_prev lives in registers of the Ph2 block that owns batch b = bx
  float hpv[4];
  if (bx < 64) {
    int j0 = tid * 4;
#pragma unroll
    for (int ii = 0; ii < 4; ++ii) hpv[ii] = memory[bx * 1024 + j0 + ii];
  }

  for (int t = 0; t < T_; ++t) {
    // ---- Ph1: gi = ctx_t @ wih2^T, gh = h_{t-1} @ whh^T (192 blocks) ----
    {
      const u16 *Ah, *Al, *Bh, *Bl;
      float* outp;
      int Br;
      if (bx < 96) {
        int nt = bx % 48, kc = bx / 48;
        Ah = dctx_h + (long)t * 65536 + kc * 512;   // rotated: first touch
        Al = dctx_l + (long)t * 65536 + kc * 512;
        Bh = wih_h + 1024 + (long)nt * 64 * 2048 + kc * 512;
        Bl = wih_l + 1024 + (long)nt * 64 * 2048 + kc * 512;
        Br = 2048;
        outp = gip + (long)kc * 196608 + nt * 64;
      } else {
        int j2 = bx - 96;
        int nt = j2 % 48, kc = j2 / 48;
        Ah = hh_r + (long)t * 65536 + kc * 512;     // slot t = h_{t-1}
        Al = hl_r + (long)t * 65536 + kc * 512;
        Bh = whh_h + (long)nt * 64 * 1024 + kc * 512;
        Bl = whh_l + (long)nt * 64 * 1024 + kc * 512;
        Br = 1024;
        outp = ghp + (long)kc * 196608 + nt * 64;
      }
      f32x4 acc[2][2];
#pragma unroll
      for (int i = 0; i < 2; ++i)
#pragma unroll
        for (int j = 0; j < 2; ++j) acc[i][j] = z4;
      gemm64_tile(Ah, Al, 1024, Bh, Bl, Br, 16, L, acc);
#pragma unroll
      for (int mi = 0; mi < 2; ++mi)
#pragma unroll
        for (int ni = 0; ni < 2; ++ni)
#pragma unroll
          for (int e = 0; e < 4; ++e) {
            int r = (wm << 5) + (mi << 4) + (kq << 2) + e;
            int c = (wn << 5) + (ni << 4) + l15;
            astore_f32(outp + (long)r * 3072 + c, acc[mi][ni][e]);
          }
    }
    gridbar(flags, seq++);

    // ---- Ph2: GRU + attention (64 blocks) ----
    if (bx < 64) {
      int b = bx;
      float* hs = (float*)L;
      float* sc_s = (float*)(L + 4096);
      float* at_s = (float*)(L + 4352);
      const float* ebase = embi + ((long)t * 64 + b) * 3072;
      {
        int j0 = tid * 4;
        // burst all gate partials (atomic: gip/ghp are reused buffers)
        float gA[3][4], gB[3][4], hA[3][4], hB[3][4];
#pragma unroll
        for (int g = 0; g < 3; ++g) {
          aload4f(gip + b * 3072 + g * 1024 + j0, gA[g]);
          aload4f(gip + 196608 + b * 3072 + g * 1024 + j0, gB[g]);
          aload4f(ghp + b * 3072 + g * 1024 + j0, hA[g]);
          aload4f(ghp + 196608 + b * 3072 + g * 1024 + j0, hB[g]);
        }
        u64 ph = 0, pl = 0;
#pragma unroll
        for (int ii = 0; ii < 4; ++ii) {
          float ir = ebase[j0 + ii] + gA[0][ii] + gB[0][ii] + bih[j0 + ii];
          float iz = ebase[1024 + j0 + ii] + gA[1][ii] + gB[1][ii] + bih[1024 + j0 + ii];
          float in2 = ebase[2048 + j0 + ii] + gA[2][ii] + gB[2][ii] + bih[2048 + j0 + ii];
          float hr = hA[0][ii] + hB[0][ii] + bhh[j0 + ii];
          float hz = hA[1][ii] + hB[1][ii] + bhh[1024 + j0 + ii];
          float hn = hA[2][ii] + hB[2][ii] + bhh[2048 + j0 + ii];
          float r = 1.f / (1.f + expf(-(ir + hr)));
          float z = 1.f / (1.f + expf(-(iz + hz)));
          float n = tanhf(in2 + r * hn);
          float h = (1.f - z) * n + z * hpv[ii];
          hpv[ii] = h;
          hs[j0 + ii] = h;
          u16 hi, lo;
          split2(h, &hi, &lo);
          ph |= (u64)hi << (16 * ii);
          pl |= (u64)lo << (16 * ii);
          if (t == T_ - 1) dout[HID_OFF + (long)b * 1024 + j0 + ii] = h;
        }
        astore_u64(hh_r + (long)(t + 1) * 65536 + b * 1024 + j0, ph);
        astore_u64(hl_r + (long)(t + 1) * 65536 + b * 1024 + j0, pl);
      }
      __syncthreads();
      {
        int s = tid >> 2, part = tid & 3;
        const float4* er = (const float4*)(encT + ((long)b * 64 + s) * 1024);
        const float4* hv = (const float4*)hs;
        float dot = 0.f;
        for (int q = part; q < 256; q += 4) {
          float4 e = er[q], h4 = hv[q];
          dot += e.x * h4.x + e.y * h4.y + e.z * h4.z + e.w * h4.w;
        }
        dot += __shfl_xor(dot, 1);
        dot += __shfl_xor(dot, 2);
        if (part == 0) sc_s[s] = dot;
      }
      __syncthreads();
      if (tid < 64) {
        int len = xs_len[b];
        float v = sc_s[tid];
        if (tid >= len || v == 0.0f) v = -1e10f;
        float m = v;
#pragma unroll
        for (int off = 32; off; off >>= 1) m = fmaxf(m, __shfl_xor(m, off));
        float p = expf(v - m);
        float sum = p;
#pragma unroll
        for (int off = 32; off; off >>= 1) sum += __shfl_xor(sum, off);
        float a = p / sum;
        at_s[tid] = a;
        dout[ATT_OFF + ((long)b * T_ + t) * S_ + tid] = a;
      }
      __syncthreads();
      {
        // attnctx = attn @ encL[b]  (f32, cached loads)
        const float4* elb = (const float4*)(encL + (long)b * 64 * 1024);
        float c0 = 0.f, c1 = 0.f, c2 = 0.f, c3 = 0.f;
        for (int s2 = 0; s2 < 64; ++s2) {
          float a = at_s[s2];
          float4 e4 = elb[s2 * 256 + tid];
          c0 += a * e4.x; c1 += a * e4.y; c2 += a * e4.z; c3 += a * e4.w;
        }
        int k0 = tid * 4;
        u64 w0 = ((u64)__float_as_uint(c1) << 32) | __float_as_uint(c0);
        u64 w1 = ((u64)__float_as_uint(c3) << 32) | __float_as_uint(c2);
        astore_u64(attnctx + b * 1024 + k0, w0);
        astore_u64(attnctx + b * 1024 + k0 + 2, w1);
      }
    }
    gridbar(flags, seq++);

    // ---- Ph3: ctx_{t+1} = tanh(attnctx + h_t @ l2b^T) (16 blocks) ----
    if (bx < 16) {
      int n0 = bx * 64;
      // stage attnctx tile (64 rows x 64 cols) into LDS via atomic burst
      {
        int rr = tid >> 2, cg = tid & 3;
        float* dstf = (float*)(L + 16384);
        const float* srcp = attnctx + rr * 1024 + n0 + cg * 16;
        float tmp[16];
#pragma unroll
        for (int k = 0; k < 8; ++k) {
          u64 v = aload_u64(srcp + k * 2);
          tmp[k * 2] = __uint_as_float((unsigned)v);
          tmp[k * 2 + 1] = __uint_as_float((unsigned)(v >> 32));
        }
#pragma unroll
        for (int k = 0; k < 16; ++k) dstf[rr * 64 + cg * 16 + k] = tmp[k];
      }
      f32x4 acc[2][2];
#pragma unroll
      for (int i = 0; i < 2; ++i)
#pragma unroll
        for (int j = 0; j < 2; ++j) acc[i][j] = z4;
      gemm64_tile(hh_r + (long)(t + 1) * 65536, hl_r + (long)(t + 1) * 65536, 1024,
                  l2_h + 1024 + (long)n0 * 2048, l2_l + 1024 + (long)n0 * 2048, 2048,
                  32, L, acc);
      __syncthreads();
      float* cf = (float*)(L + 16384);
#pragma unroll
      for (int mi = 0; mi < 2; ++mi)
#pragma unroll
        for (int ni = 0; ni < 2; ++ni)
#pragma unroll
          for (int e = 0; e < 4; ++e) {
            int r = (wm << 5) + (mi << 4) + (kq << 2) + e;
            int c = (wn << 5) + (ni << 4) + l15;
            cf[r * 64 + c] = tanhf(acc[mi][ni][e] + cf[r * 64 + c]);
          }
      __syncthreads();
      {
        int rr = tid >> 2, cg = tid & 3;
        long obase = (long)(t + 1) * 65536 + (long)rr * 1024 + n0 + cg * 16;
#pragma unroll
        for (int g = 0; g < 4; ++g) {
          u64 ph = 0, pl = 0;
#pragma unroll
          for (int ii = 0; ii < 4; ++ii) {
            float v = cf[rr * 64 + cg * 16 + g * 4 + ii];
            u16 hi, lo;
            split2(v, &hi, &lo);
            ph |= (u64)hi << (16 * ii);
            pl |= (u64)lo << (16 * ii);
            if (t == T_ - 1) dout[CTF_OFF + (long)rr * 1024 + n0 + cg * 16 + g * 4 + ii] = v;
          }
          astore_u64(dctx_h + obase + g * 4, ph);
          astore_u64(dctx_l + obase + g * 4, pl);
        }
      }
    }
    gridbar(flags, seq++);
  }
}

// ---------------- in-place log-softmax over V per row ----------------
__device__ __forceinline__ void lse_comb(float& m, float& s, float mo, float so) {
  float M = fmaxf(m, mo);
  s = s * __expf(m - M) + so * __expf(mo - M);
  m = M;
}

__launch_bounds__(256)
__global__ void k_lsm(float* __restrict__ dout) {
  long base = (long)blockIdx.x * V_;
  int tid = threadIdx.x;
  float m = -3.0e38f, s = 0.f;
  for (int v = tid; v < V_; v += 256) {
    float x = dout[base + v];
    if (x > m) {
      s = s * __expf(m - x) + 1.f;
      m = x;
    } else {
      s += __expf(x - m);
    }
  }
#pragma unroll
  for (int off = 32; off; off >>= 1) {
    float mo = __shfl_xor(m, off), so = __shfl_xor(s, off);
    lse_comb(m, s, mo, so);
  }
  __shared__ float ms[4], ss[4];
  if ((tid & 63) == 0) { ms[tid >> 6] = m; ss[tid >> 6] = s; }
  __syncthreads();
  float M = ms[0], S = ss[0];
  for (int w2 = 1; w2 < 4; ++w2) lse_comb(M, S, ms[w2], ss[w2]);
  float logden = M + logf(S);
  for (int v = tid; v < V_; v += 256) dout[base + v] -= logden;
}

// ---------------- host launcher ----------------
extern "C" void kernel_launch(void* const* d_in, const int* in_sizes, int n_in,
                              void* d_out, int out_size, void* d_ws, size_t ws_size,
                              hipStream_t stream) {
  (void)in_sizes; (void)n_in; (void)out_size;
  const int* input = (const int*)d_in[0];
  const float* memory = (const float*)d_in[1];
  const float* enc = (const float*)d_in[2];
  const int* xs_len = (const int*)d_in[3];
  const float* emb = (const float*)d_in[4];
  const float* wih = (const float*)d_in[5];
  const float* whh = (const float*)d_in[6];
  const float* bih = (const float*)d_in[7];
  const float* bhh = (const float*)d_in[8];
  const float* l1 = (const float*)d_in[9];
  const float* l2 = (const float*)d_in[10];
  const float* wout = (const float*)d_in[11];
  const float* bout = (const float*)d_in[12];
  float* out = (float*)d_out;
  char* w = (char*)d_ws;

  size_t off = 0;
  auto alloc = [&](size_t bytes) {
    size_t o = off;
    off = (off + bytes + 255) & ~(size_t)255;
    return o;
  };
  const size_t N_WIH = 3072UL * 2048, N_WHH = 3072UL * 1024, N_L2 = 1024UL * 2048;
  const size_t N_L1 = 1024UL * 1024, N_ENC = 4096UL * 1024, N_WOUT = 32000UL * 1024;
  const size_t N_EMBX = 2048UL * 1024, N_ENCT = 4096UL * 1024;
  const size_t N_EMBI = 2048UL * 3072, N_ROT = 33UL * 65536;

  // persistent
  size_t o_wih_h = alloc(2 * N_WIH), o_wih_l = alloc(2 * N_WIH);
  size_t o_whh_h = alloc(2 * N_WHH), o_whh_l = alloc(2 * N_WHH);
  size_t o_l2_h = alloc(2 * N_L2), o_l2_l = alloc(2 * N_L2);
  size_t o_l1t_h = alloc(2 * N_L1), o_l1t_l = alloc(2 * N_L1);
  size_t o_ctx_h = alloc(2 * N_ROT), o_ctx_l = alloc(2 * N_ROT);
  size_t o_hh = alloc(2 * N_ROT), o_hl = alloc(2 * N_ROT);
  size_t o_gip = alloc(4 * 2 * 196608), o_ghp = alloc(4 * 2 * 196608);
  size_t o_actx = alloc(4 * 65536);
  size_t o_bar = alloc(16384);
  // arena: prep-only buffers; wout_b (64 MB) overlays them after k_rec
  size_t o_arena = alloc(2 * N_ENC * 2 + 2 * N_EMBX * 2 + 4 * N_EMBI + 4 * N_ENCT * 2);

  if (off > ws_size) {
    k_guard<<<1, 1, 0, stream>>>(out, 1.0e8f + (float)(ws_size >> 20));
    return;
  }

  u16* wih_h = (u16*)(w + o_wih_h);   u16* wih_l = (u16*)(w + o_wih_l);
  u16* whh_h = (u16*)(w + o_whh_h);   u16* whh_l = (u16*)(w + o_whh_l);
  u16* l2_h = (u16*)(w + o_l2_h);     u16* l2_l = (u16*)(w + o_l2_l);
  u16* l1t_h = (u16*)(w + o_l1t_h);   u16* l1t_l = (u16*)(w + o_l1t_l);
  u16* ctx_h = (u16*)(w + o_ctx_h);   u16* ctx_l = (u16*)(w + o_ctx_l);
  u16* hh_r = (u16*)(w + o_hh);       u16* hl_r = (u16*)(w + o_hl);
  float* gip = (float*)(w + o_gip);
  float* ghp = (float*)(w + o_ghp);
  float* actx = (float*)(w + o_actx);
  unsigned* flags = (unsigned*)(w + o_bar);

  char* ar = w + o_arena;
  u16* enc_h = (u16*)ar;                       // 8.4 MB
  u16* enc_l = (u16*)(ar + 2 * N_ENC);         // 8.4 MB
  u16* embx_h = (u16*)(ar + 4 * N_ENC);        // 4.2 MB
  u16* embx_l = (u16*)(ar + 4 * N_ENC + 2 * N_EMBX);
  float* embi = (float*)(ar + 4 * N_ENC + 4 * N_EMBX);          // 25.2 MB
  float* encT = (float*)(ar + 4 * N_ENC + 4 * N_EMBX + 4 * N_EMBI);
  float* encL = (float*)(ar + 4 * N_ENC + 4 * N_EMBX + 4 * N_EMBI + 4 * N_ENCT);
  u16* wout_b = (u16*)ar;  // overlays enc/embx/embi after k_rec (65.5 MB)

  // prep
  k_split<<<2048, 256, 0, stream>>>(wih, wih_h, wih_l, (int)N_WIH);
  k_split<<<2048, 256, 0, stream>>>(whh, whh_h, whh_l, (int)N_WHH);
  k_split<<<2048, 256, 0, stream>>>(l2, l2_h, l2_l, (int)N_L2);
  k_split<<<2048, 256, 0, stream>>>(enc, enc_h, enc_l, (int)N_ENC);
  k_l1t<<<256, 256, 0, stream>>>(l1, l1t_h, l1t_l);
  k_embx<<<2048, 256, 0, stream>>>(input, emb, embx_h, embx_l);
  k_h0<<<256, 256, 0, stream>>>(memory, hh_r, hl_r);
  hipMemsetAsync(ctx_h, 0, 131072, stream);  // ctx slot 0 = zeros
  hipMemsetAsync(ctx_l, 0, 131072, stream);
  hipMemsetAsync(flags, 0, 16384, stream);

  // encT = enc @ l1^T(T)  ; encL = enc @ l2a^T ; embi = embx @ w_ih[:, :1024]^T
  k_gemm128<1, 0><<<256, 256, 0, stream>>>(enc_h, enc_l, l1t_h, l1t_l, encT, nullptr,
                                           32, 8, 1024, 1024, 1024, 1024);
  k_gemm128<1, 0><<<256, 256, 0, stream>>>(enc_h, enc_l, l2_h, l2_l, encL, nullptr,
                                           32, 8, 1024, 1024, 2048, 1024);
  k_gemm128<1, 0><<<384, 256, 0, stream>>>(embx_h, embx_l, wih_h, wih_l, embi, nullptr,
                                           16, 24, 1024, 1024, 2048, 3072);

  // persistent recurrence (192 blocks, 3 barriers/step)
  k_rec<<<NB_, 256, 0, stream>>>(embi, ctx_h, ctx_l, hh_r, hl_r, memory,
                                 wih_h, wih_l, whh_h, whh_l, l2_h, l2_l,
                                 gip, ghp, actx, encT, encL, xs_len,
                                 bih, bhh, out, flags);

  // wout -> bf16 (after k_rec so it can overlay the dead prep arena)
  k_tobf<<<4096, 256, 0, stream>>>(wout, wout_b, (int)N_WOUT);

  // logits = dctx_all @ w_out^T + b_out, scattered to [b][t][v]
  k_gemm128<0, 1><<<4000, 256, 0, stream>>>(ctx_h + 65536, nullptr, wout_b, nullptr,
                                            out, bout, 16, 250, 1024, 1024, 1024, 0);
  // in-place log-softmax per (b,t) row
  k_lsm<<<2048, 256, 0, stream>>>(out);
}

// Round 5
// 2760.754 us; speedup vs baseline: 1.0837x; 1.0837x over previous
//
#include <hip/hip_runtime.h>

// ---------------------------------------------------------------------------
// AttentionDecoder: B=64 T=32 S=64 H=1024 V=32000
// R5: persistent recurrence with LDS-RESIDENT WEIGHTS.
//  - All recurrence weights (wih2, whh, l2b hi/lo = 29.4 MB) are loaded ONCE
//    into per-block LDS slabs (131 KB x 224 blocks) before the t-loop.
//    Per-step HBM traffic drops from ~35 MB (R4, L2 thrash) to ~2 MB.
//  - encT/encL (32 MB) become the sole large L2 tenant (4 MB/XCD) -> resident.
//  - Coherence protocol from R4 (proven): producers atomic-store to the
//    memory-side coherent point; consumers either atomic-load (reused bufs)
//    or normal-load rotation-fresh buffers (first touch -> clean L2 miss).
//  - 224 blocks, 152 KB dynamic LDS, 3 grid barriers/step:
//      Ph1: gi = dctx@wih2^T (96 blk), gh = h@whh^T (96 blk), BK=64, K=512
//      Ph2: GRU finalize + scores(encT) + softmax + attnctx(encL) (64 blk)
//      Ph3: dctx[t+1] = tanh(attnctx + h@l2b^T) (32 blk, full-K, 32-N)
//  - Logits GEMM + log-softmax unchanged.
// ---------------------------------------------------------------------------

#define B_ 64
#define T_ 32
#define S_ 64
#define H_ 1024
#define V_ 32000
#define NB_ 224
#define LDS_BYTES 152064
// LDS layout: [0,65536) W_HI  [65536,131072) W_LO
//             [131072,139264) A_HI (2 subtiles)  [139264,147456) A_LO
//             [147456,152064) Ph2 scratch (hs 4096, sc 256, at 256)
//             Ph3 reuses [131072,139264) as f32 C-tile (8 KB)

#define HID_OFF 65536000L
#define ATT_OFF 65601536L
#define CTF_OFF 65732608L

typedef __attribute__((ext_vector_type(8))) short bf16x8;
typedef __attribute__((ext_vector_type(4))) float f32x4;
typedef __attribute__((ext_vector_type(4))) unsigned int u32x4;
typedef unsigned short u16;
typedef unsigned long long u64;

__device__ __forceinline__ u16 f2bf(float v) {
  unsigned int u = __float_as_uint(v);
  unsigned int r = (u + 0x7fffu + ((u >> 16) & 1u)) >> 16;  // RNE
  return (u16)r;
}
__device__ __forceinline__ float bf2f(u16 h) {
  return __uint_as_float(((unsigned int)h) << 16);
}
__device__ __forceinline__ void split2(float v, u16* hi, u16* lo) {
  u16 h = f2bf(v);
  *hi = h;
  *lo = f2bf(v - bf2f(h));
}

// ---- coherent-path (agent-scope relaxed atomic) helpers ----
__device__ __forceinline__ u64 aload_u64(const void* p) {
  return __hip_atomic_load((const u64*)p, __ATOMIC_RELAXED, __HIP_MEMORY_SCOPE_AGENT);
}
__device__ __forceinline__ unsigned aload_u32(const void* p) {
  return __hip_atomic_load((const unsigned*)p, __ATOMIC_RELAXED, __HIP_MEMORY_SCOPE_AGENT);
}
__device__ __forceinline__ void astore_u64(void* p, u64 v) {
  __hip_atomic_store((u64*)p, v, __ATOMIC_RELAXED, __HIP_MEMORY_SCOPE_AGENT);
}
__device__ __forceinline__ void astore_f32(float* p, float v) {
  __hip_atomic_store((unsigned*)p, __float_as_uint(v), __ATOMIC_RELAXED,
                     __HIP_MEMORY_SCOPE_AGENT);
}
__device__ __forceinline__ void aload4f(const float* p, float* d) {
  u64 a = aload_u64(p), b = aload_u64(p + 2);
  d[0] = __uint_as_float((unsigned)a);
  d[1] = __uint_as_float((unsigned)(a >> 32));
  d[2] = __uint_as_float((unsigned)b);
  d[3] = __uint_as_float((unsigned)(b >> 32));
}

// ---------------- conversion / prep kernels ----------------

__global__ void k_split(const float* __restrict__ src, u16* __restrict__ hi,
                        u16* __restrict__ lo, int n) {
  int i = blockIdx.x * blockDim.x + threadIdx.x;
  int stride = gridDim.x * blockDim.x;
  for (; i < n; i += stride) split2(src[i], &hi[i], &lo[i]);
}

__global__ void k_tobf(const float* __restrict__ src, u16* __restrict__ dst, int n) {
  int i = blockIdx.x * blockDim.x + threadIdx.x;
  int stride = gridDim.x * blockDim.x;
  for (; i < n; i += stride) dst[i] = f2bf(src[i]);
}

// l1 (H,H) row-major [i][k] -> l1T hi/lo [k][i]
__global__ void k_l1t(const float* __restrict__ l1, u16* __restrict__ hi,
                      u16* __restrict__ lo) {
  __shared__ float tile[64][65];
  int it = blockIdx.x & 15, kt = blockIdx.x >> 4;
  for (int q = 0; q < 16; ++q) {
    int idx = q * 256 + threadIdx.x;
    int r = idx >> 6, c = idx & 63;
    tile[r][c] = l1[(long)(it * 64 + r) * H_ + kt * 64 + c];
  }
  __syncthreads();
  for (int q = 0; q < 16; ++q) {
    int idx = q * 256 + threadIdx.x;
    int r = idx >> 6, c = idx & 63;
    long o = (long)(kt * 64 + r) * H_ + it * 64 + c;
    split2(tile[c][r], &hi[o], &lo[o]);
  }
}

// gather embeddings: embx[t][b][k] hi/lo
__global__ void k_embx(const int* __restrict__ inp, const float* __restrict__ emb,
                       u16* __restrict__ hi, u16* __restrict__ lo) {
  int bt = blockIdx.x;
  int b = bt >> 5, t = bt & 31;
  int id = inp[b * T_ + t];
  const float* src = emb + (long)id * H_;
  long base = (long)(t * B_ + b) * H_;
  for (int k = threadIdx.x; k < H_; k += 256) split2(src[k], &hi[base + k], &lo[base + k]);
}

// h0 -> hh_r/hl_r slot 0
__global__ void k_h0(const float* __restrict__ mem, u16* __restrict__ hh,
                     u16* __restrict__ hl) {
  int i = blockIdx.x * 256 + threadIdx.x;  // 65536
  float v = mem[i];
  split2(v, &hh[i], &hl[i]);
}

__global__ void k_guard(float* out, float v) {
  if (blockIdx.x == 0 && threadIdx.x == 0) out[0] = v;
}

// ---------------- 128x128 tile GEMM (BK=32), optional split-bf16 ----------------
template <int SPLIT, int OMODE>
__launch_bounds__(256)
__global__ void k_gemm128(const u16* __restrict__ Ah, const u16* __restrict__ Al,
                          const u16* __restrict__ Bh, const u16* __restrict__ Bl,
                          float* __restrict__ C, const float* __restrict__ bias,
                          int Mtiles, int Ntiles, int K, int Arow, int Brow, int Crow) {
  (void)Ntiles;
  int bx = blockIdx.x;
  int mt = bx % Mtiles, nt = bx / Mtiles;
  int m0 = mt * 128, n0 = nt * 128;

  __shared__ __attribute__((aligned(16))) u16 lds[(SPLIT ? 4 : 2) * 4096];
  char* L = (char*)lds;
  const int tid = threadIdx.x;
  const int lane = tid & 63, wid = tid >> 6;
  const int wm = wid & 1, wn = wid >> 1;
  const int l15 = lane & 15, kq = lane >> 4;

  f32x4 acc[4][4];
  const f32x4 z4 = {0.f, 0.f, 0.f, 0.f};
#pragma unroll
  for (int i = 0; i < 4; ++i)
#pragma unroll
    for (int j = 0; j < 4; ++j) acc[i][j] = z4;

  const int ksteps = K >> 5;
  for (int kt = 0; kt < ksteps; ++kt) {
    __syncthreads();
#pragma unroll
    for (int h2 = 0; h2 < 2; ++h2) {
      int r = (tid >> 2) + (h2 << 6);
      int slot = tid & 3;
      int so = ((slot ^ (r & 3)) << 4);
      long ga = (long)(m0 + r) * Arow + (kt << 5) + (slot << 3);
      long gb = (long)(n0 + r) * Brow + (kt << 5) + (slot << 3);
      *(u32x4*)(L + r * 64 + so) = *(const u32x4*)(Ah + ga);
      *(u32x4*)(L + 8192 + r * 64 + so) = *(const u32x4*)(Bh + gb);
      if (SPLIT) {
        *(u32x4*)(L + 16384 + r * 64 + so) = *(const u32x4*)(Al + ga);
        *(u32x4*)(L + 24576 + r * 64 + so) = *(const u32x4*)(Bl + gb);
      }
    }
    __syncthreads();
    bf16x8 aH[4], bH[4], aL[4], bL[4];
#pragma unroll
    for (int mi = 0; mi < 4; ++mi) {
      int r = (wm << 6) + (mi << 4) + l15;
      int off = r * 64 + ((kq ^ (r & 3)) << 4);
      aH[mi] = *(const bf16x8*)(L + off);
      if (SPLIT) aL[mi] = *(const bf16x8*)(L + 16384 + off);
    }
#pragma unroll
    for (int ni = 0; ni < 4; ++ni) {
      int c = (wn << 6) + (ni << 4) + l15;
      int off = c * 64 + ((kq ^ (c & 3)) << 4);
      bH[ni] = *(const bf16x8*)(L + 8192 + off);
      if (SPLIT) bL[ni] = *(const bf16x8*)(L + 24576 + off);
    }
#pragma unroll
    for (int mi = 0; mi < 4; ++mi)
#pragma unroll
      for (int ni = 0; ni < 4; ++ni) {
        acc[mi][ni] = __builtin_amdgcn_mfma_f32_16x16x32_bf16(aH[mi], bH[ni], acc[mi][ni], 0, 0, 0);
        if (SPLIT) {
          acc[mi][ni] = __builtin_amdgcn_mfma_f32_16x16x32_bf16(aL[mi], bH[ni], acc[mi][ni], 0, 0, 0);
          acc[mi][ni] = __builtin_amdgcn_mfma_f32_16x16x32_bf16(aH[mi], bL[ni], acc[mi][ni], 0, 0, 0);
        }
      }
  }
#pragma unroll
  for (int mi = 0; mi < 4; ++mi)
#pragma unroll
    for (int ni = 0; ni < 4; ++ni)
#pragma unroll
      for (int e = 0; e < 4; ++e) {
        int r = (wm << 6) + (mi << 4) + (kq << 2) + e;
        int c = (wn << 6) + (ni << 4) + l15;
        int gm = m0 + r, gn = n0 + c;
        float v = acc[mi][ni][e];
        if (OMODE == 0) {
          C[(long)gm * Crow + gn] = v;
        } else {
          v += bias[gn];
          C[((long)(gm & 63) * T_ + (gm >> 6)) * V_ + gn] = v;
        }
      }
}

// ---------------- grid barrier: release flag + distributed relaxed poll ----
__device__ __forceinline__ void gridbar(unsigned* flags, unsigned seq) {
  __syncthreads();
  if (threadIdx.x == 0)
    __hip_atomic_store(flags + blockIdx.x * 16, seq, __ATOMIC_RELEASE,
                       __HIP_MEMORY_SCOPE_AGENT);
  if (threadIdx.x < 64) {
    int l = threadIdx.x;
    for (;;) {
      unsigned a = __hip_atomic_load(flags + l * 16, __ATOMIC_RELAXED, __HIP_MEMORY_SCOPE_AGENT);
      unsigned b = __hip_atomic_load(flags + (l + 64) * 16, __ATOMIC_RELAXED, __HIP_MEMORY_SCOPE_AGENT);
      unsigned c = __hip_atomic_load(flags + (l + 128) * 16, __ATOMIC_RELAXED, __HIP_MEMORY_SCOPE_AGENT);
      unsigned d = (l < NB_ - 192) ? __hip_atomic_load(flags + (l + 192) * 16, __ATOMIC_RELAXED, __HIP_MEMORY_SCOPE_AGENT) : seq;
      if (__all((a >= seq) & (b >= seq) & (c >= seq) & (d >= seq))) break;
      __builtin_amdgcn_s_sleep(1);
    }
  }
  __syncthreads();
}

// ---------------- persistent recurrence kernel ----------------
__launch_bounds__(256)
__global__ void k_rec(const float* __restrict__ embi,
                      u16* __restrict__ dctx_h, u16* __restrict__ dctx_l,
                      u16* __restrict__ hh_r, u16* __restrict__ hl_r,
                      const float* __restrict__ memory,
                      const u16* __restrict__ wih_h, const u16* __restrict__ wih_l,
                      const u16* __restrict__ whh_h, const u16* __restrict__ whh_l,
                      const u16* __restrict__ l2_h, const u16* __restrict__ l2_l,
                      float* __restrict__ gip, float* __restrict__ ghp,
                      float* __restrict__ attnctx,
                      const float* __restrict__ encT, const float* __restrict__ encL,
                      const int* __restrict__ xs_len,
                      const float* __restrict__ bih, const float* __restrict__ bhh,
                      float* __restrict__ dout, unsigned* flags) {
  extern __shared__ __attribute__((aligned(16))) char L[];
  char* W_HI = L;
  char* W_LO = L + 65536;
  char* A_HI = L + 131072;
  char* A_LO = L + 139264;
  const int bx = blockIdx.x;
  const int tid = threadIdx.x;
  const int lane = tid & 63, wid = tid >> 6;
  const int wm = wid & 1, wn = wid >> 1;
  const int l15 = lane & 15, kq = lane >> 4;
  const f32x4 z4 = {0.f, 0.f, 0.f, 0.f};
  unsigned seq = 1;

  // ---- role decode ----
  const int isGI = (bx < 96);
  const int isGH = (bx >= 96 && bx < 192);
  const int isL2 = (bx >= 192);
  int nt = 0, kc = 0, n0 = 0;
  const u16 *Wg_h = nullptr, *Wg_l = nullptr;
  int wrs = 0;
  if (isGI) {
    nt = bx % 48; kc = bx / 48;
    Wg_h = wih_h + 1024 + (long)nt * 64 * 2048 + kc * 512;
    Wg_l = wih_l + 1024 + (long)nt * 64 * 2048 + kc * 512;
    wrs = 2048;
  } else if (isGH) {
    int j2 = bx - 96;
    nt = j2 % 48; kc = j2 / 48;
    Wg_h = whh_h + (long)nt * 64 * 1024 + kc * 512;
    Wg_l = whh_l + (long)nt * 64 * 1024 + kc * 512;
    wrs = 1024;
  } else {
    n0 = (bx - 192) << 5;
    Wg_h = l2_h + 1024 + (long)n0 * 2048;
    Wg_l = l2_l + 1024 + (long)n0 * 2048;
    wrs = 2048;
  }

  // ---- one-time: load weight slab into LDS (131 KB) ----
  if (!isL2) {
    // 16 subtiles of (64 rows x 32 K), each 4096 B
    for (int e = tid; e < 4096; e += 256) {
      int st = e >> 8, r = (e >> 2) & 63, slot = e & 3;
      long g = (long)r * wrs + st * 32 + slot * 8;
      int o = st * 4096 + r * 64 + ((slot ^ (r & 3)) << 4);
      *(u32x4*)(W_HI + o) = *(const u32x4*)(Wg_h + g);
      *(u32x4*)(W_LO + o) = *(const u32x4*)(Wg_l + g);
    }
  } else {
    // 32 subtiles of (32 rows x 32 K), each 2048 B
    for (int e = tid; e < 4096; e += 256) {
      int st = e >> 7, r = (e >> 2) & 31, slot = e & 3;
      long g = (long)r * wrs + st * 32 + slot * 8;
      int o = st * 2048 + r * 64 + ((slot ^ (r & 3)) << 4);
      *(u32x4*)(W_HI + o) = *(const u32x4*)(Wg_h + g);
      *(u32x4*)(W_LO + o) = *(const u32x4*)(Wg_l + g);
    }
  }
  __syncthreads();

  // h_prev in registers for Ph2 block b = bx
  float hpv[4];
  if (bx < 64) {
    int j0 = tid * 4;
#pragma unroll
    for (int ii = 0; ii < 4; ++ii) hpv[ii] = memory[bx * 1024 + j0 + ii];
  }

  // A-staging thread constants
  const int pr = tid >> 2, ps = tid & 3;
  const int ao = pr * 64 + ((ps ^ (pr & 3)) << 4);

  for (int t = 0; t < T_; ++t) {
    // ================= Ph1: gates GEMMs (blocks 0..191) =================
    if (!isL2) {
      const u16* Ah;
      const u16* Al;
      float* outp;
      if (isGI) {
        Ah = dctx_h + (long)t * 65536 + kc * 512;   // rotation-fresh
        Al = dctx_l + (long)t * 65536 + kc * 512;
        outp = gip + (long)kc * 196608 + nt * 64;
      } else {
        Ah = hh_r + (long)t * 65536 + kc * 512;
        Al = hl_r + (long)t * 65536 + kc * 512;
        outp = ghp + (long)kc * 196608 + nt * 64;
      }
      const long g0 = (long)pr * 1024 + ps * 8;
      u32x4 ph0 = *(const u32x4*)(Ah + g0);
      u32x4 ph1 = *(const u32x4*)(Ah + g0 + 32);
      u32x4 pl0 = *(const u32x4*)(Al + g0);
      u32x4 pl1 = *(const u32x4*)(Al + g0 + 32);

      f32x4 acc[2][2];
#pragma unroll
      for (int i = 0; i < 2; ++i)
#pragma unroll
        for (int j = 0; j < 2; ++j) acc[i][j] = z4;

      for (int kt = 0; kt < 8; ++kt) {
        __syncthreads();
        *(u32x4*)(A_HI + ao) = ph0;
        *(u32x4*)(A_HI + 4096 + ao) = ph1;
        *(u32x4*)(A_LO + ao) = pl0;
        *(u32x4*)(A_LO + 4096 + ao) = pl1;
        __syncthreads();
        if (kt < 7) {
          long g = g0 + (kt + 1) * 64;
          ph0 = *(const u32x4*)(Ah + g);
          ph1 = *(const u32x4*)(Ah + g + 32);
          pl0 = *(const u32x4*)(Al + g);
          pl1 = *(const u32x4*)(Al + g + 32);
        }
#pragma unroll
        for (int sub = 0; sub < 2; ++sub) {
          const int stw = (kt * 2 + sub) * 4096;
          const int sta = sub * 4096;
          bf16x8 aH[2], aL[2], bH[2], bL[2];
#pragma unroll
          for (int mi = 0; mi < 2; ++mi) {
            int rr = (wm << 5) + (mi << 4) + l15;
            int off = rr * 64 + ((kq ^ (rr & 3)) << 4);
            aH[mi] = *(const bf16x8*)(A_HI + sta + off);
            aL[mi] = *(const bf16x8*)(A_LO + sta + off);
          }
#pragma unroll
          for (int ni = 0; ni < 2; ++ni) {
            int c = (wn << 5) + (ni << 4) + l15;
            int off = c * 64 + ((kq ^ (c & 3)) << 4);
            bH[ni] = *(const bf16x8*)(W_HI + stw + off);
            bL[ni] = *(const bf16x8*)(W_LO + stw + off);
          }
#pragma unroll
          for (int mi = 0; mi < 2; ++mi)
#pragma unroll
            for (int ni = 0; ni < 2; ++ni) {
              acc[mi][ni] = __builtin_amdgcn_mfma_f32_16x16x32_bf16(aH[mi], bH[ni], acc[mi][ni], 0, 0, 0);
              acc[mi][ni] = __builtin_amdgcn_mfma_f32_16x16x32_bf16(aL[mi], bH[ni], acc[mi][ni], 0, 0, 0);
              acc[mi][ni] = __builtin_amdgcn_mfma_f32_16x16x32_bf16(aH[mi], bL[ni], acc[mi][ni], 0, 0, 0);
            }
        }
      }
#pragma unroll
      for (int mi = 0; mi < 2; ++mi)
#pragma unroll
        for (int ni = 0; ni < 2; ++ni)
#pragma unroll
          for (int e = 0; e < 4; ++e) {
            int r = (wm << 5) + (mi << 4) + (kq << 2) + e;
            int c = (wn << 5) + (ni << 4) + l15;
            astore_f32(outp + (long)r * 3072 + c, acc[mi][ni][e]);
          }
    }
    gridbar(flags, seq++);

    // ================= Ph2: GRU + attention (blocks 0..63) =================
    if (bx < 64) {
      int b = bx;
      float* hs = (float*)(L + 147456);
      float* sc_s = (float*)(L + 151552);
      float* at_s = (float*)(L + 151808);
      const float* ebase = embi + ((long)t * 64 + b) * 3072;
      {
        int j0 = tid * 4;
        float gA[3][4], gB[3][4], hA[3][4], hB[3][4];
#pragma unroll
        for (int g = 0; g < 3; ++g) {
          aload4f(gip + b * 3072 + g * 1024 + j0, gA[g]);
          aload4f(gip + 196608 + b * 3072 + g * 1024 + j0, gB[g]);
          aload4f(ghp + b * 3072 + g * 1024 + j0, hA[g]);
          aload4f(ghp + 196608 + b * 3072 + g * 1024 + j0, hB[g]);
        }
        u64 ph = 0, pl = 0;
#pragma unroll
        for (int ii = 0; ii < 4; ++ii) {
          float ir = ebase[j0 + ii] + gA[0][ii] + gB[0][ii] + bih[j0 + ii];
          float iz = ebase[1024 + j0 + ii] + gA[1][ii] + gB[1][ii] + bih[1024 + j0 + ii];
          float in2 = ebase[2048 + j0 + ii] + gA[2][ii] + gB[2][ii] + bih[2048 + j0 + ii];
          float hr = hA[0][ii] + hB[0][ii] + bhh[j0 + ii];
          float hz = hA[1][ii] + hB[1][ii] + bhh[1024 + j0 + ii];
          float hn = hA[2][ii] + hB[2][ii] + bhh[2048 + j0 + ii];
          float r = 1.f / (1.f + expf(-(ir + hr)));
          float z = 1.f / (1.f + expf(-(iz + hz)));
          float n = tanhf(in2 + r * hn);
          float h = (1.f - z) * n + z * hpv[ii];
          hpv[ii] = h;
          hs[j0 + ii] = h;
          u16 hi, lo;
          split2(h, &hi, &lo);
          ph |= (u64)hi << (16 * ii);
          pl |= (u64)lo << (16 * ii);
          if (t == T_ - 1) dout[HID_OFF + (long)b * 1024 + j0 + ii] = h;
        }
        astore_u64(hh_r + (long)(t + 1) * 65536 + b * 1024 + j0, ph);
        astore_u64(hl_r + (long)(t + 1) * 65536 + b * 1024 + j0, pl);
      }
      __syncthreads();
      {
        int s = tid >> 2, part = tid & 3;
        const float4* er = (const float4*)(encT + ((long)b * 64 + s) * 1024);
        const float4* hv = (const float4*)hs;
        float dot = 0.f;
        for (int q = part; q < 256; q += 4) {
          float4 e = er[q], h4 = hv[q];
          dot += e.x * h4.x + e.y * h4.y + e.z * h4.z + e.w * h4.w;
        }
        dot += __shfl_xor(dot, 1);
        dot += __shfl_xor(dot, 2);
        if (part == 0) sc_s[s] = dot;
      }
      __syncthreads();
      if (tid < 64) {
        int len = xs_len[b];
        float v = sc_s[tid];
        if (tid >= len || v == 0.0f) v = -1e10f;
        float m = v;
#pragma unroll
        for (int off = 32; off; off >>= 1) m = fmaxf(m, __shfl_xor(m, off));
        float p = expf(v - m);
        float sum = p;
#pragma unroll
        for (int off = 32; off; off >>= 1) sum += __shfl_xor(sum, off);
        float a = p / sum;
        at_s[tid] = a;
        dout[ATT_OFF + ((long)b * T_ + t) * S_ + tid] = a;
      }
      __syncthreads();
      {
        const float4* elb = (const float4*)(encL + (long)b * 64 * 1024);
        float c0 = 0.f, c1 = 0.f, c2 = 0.f, c3 = 0.f;
        for (int s2 = 0; s2 < 64; ++s2) {
          float a = at_s[s2];
          float4 e4 = elb[s2 * 256 + tid];
          c0 += a * e4.x; c1 += a * e4.y; c2 += a * e4.z; c3 += a * e4.w;
        }
        int k0 = tid * 4;
        u64 w0 = ((u64)__float_as_uint(c1) << 32) | __float_as_uint(c0);
        u64 w1 = ((u64)__float_as_uint(c3) << 32) | __float_as_uint(c2);
        astore_u64(attnctx + b * 1024 + k0, w0);
        astore_u64(attnctx + b * 1024 + k0 + 2, w1);
      }
    }
    gridbar(flags, seq++);

    // ========== Ph3: dctx[t+1] = tanh(attnctx + h@l2b^T) (blocks 192+) =====
    if (isL2) {
      const u16* Ah = hh_r + (long)(t + 1) * 65536;   // rotation-fresh
      const u16* Al = hl_r + (long)(t + 1) * 65536;
      const long g0 = (long)pr * 1024 + ps * 8;
      u32x4 ph0 = *(const u32x4*)(Ah + g0);
      u32x4 ph1 = *(const u32x4*)(Ah + g0 + 32);
      u32x4 pl0 = *(const u32x4*)(Al + g0);
      u32x4 pl1 = *(const u32x4*)(Al + g0 + 32);

      f32x4 acc[2];
      acc[0] = z4; acc[1] = z4;
      for (int kt = 0; kt < 16; ++kt) {
        __syncthreads();
        *(u32x4*)(A_HI + ao) = ph0;
        *(u32x4*)(A_HI + 4096 + ao) = ph1;
        *(u32x4*)(A_LO + ao) = pl0;
        *(u32x4*)(A_LO + 4096 + ao) = pl1;
        __syncthreads();
        if (kt < 15) {
          long g = g0 + (kt + 1) * 64;
          ph0 = *(const u32x4*)(Ah + g);
          ph1 = *(const u32x4*)(Ah + g + 32);
          pl0 = *(const u32x4*)(Al + g);
          pl1 = *(const u32x4*)(Al + g + 32);
        }
#pragma unroll
        for (int sub = 0; sub < 2; ++sub) {
          const int stw = (kt * 2 + sub) * 2048;
          const int sta = sub * 4096;
          bf16x8 aH[2], aL[2], bH, bL;
#pragma unroll
          for (int mi = 0; mi < 2; ++mi) {
            int rr = (wm << 5) + (mi << 4) + l15;
            int off = rr * 64 + ((kq ^ (rr & 3)) << 4);
            aH[mi] = *(const bf16x8*)(A_HI + sta + off);
            aL[mi] = *(const bf16x8*)(A_LO + sta + off);
          }
          {
            int c = (wn << 4) + l15;
            int off = c * 64 + ((kq ^ (c & 3)) << 4);
            bH = *(const bf16x8*)(W_HI + stw + off);
            bL = *(const bf16x8*)(W_LO + stw + off);
          }
#pragma unroll
          for (int mi = 0; mi < 2; ++mi) {
            acc[mi] = __builtin_amdgcn_mfma_f32_16x16x32_bf16(aH[mi], bH, acc[mi], 0, 0, 0);
            acc[mi] = __builtin_amdgcn_mfma_f32_16x16x32_bf16(aL[mi], bH, acc[mi], 0, 0, 0);
            acc[mi] = __builtin_amdgcn_mfma_f32_16x16x32_bf16(aH[mi], bL, acc[mi], 0, 0, 0);
          }
        }
      }
      // epilogue: add attnctx, tanh, pack via LDS, atomic-store dctx[t+1]
      __syncthreads();
      float* cf = (float*)(L + 131072);  // 64x32 f32 = 8 KB
#pragma unroll
      for (int mi = 0; mi < 2; ++mi)
#pragma unroll
        for (int e = 0; e < 4; ++e) {
          int rr = (wm << 5) + (mi << 4) + (kq << 2) + e;
          int cc = (wn << 4) + l15;
          float a = __uint_as_float(aload_u32(attnctx + rr * 1024 + n0 + cc));
          float v = tanhf(acc[mi][e] + a);
          if (t == T_ - 1) dout[CTF_OFF + (long)rr * 1024 + n0 + cc] = v;
          cf[rr * 32 + cc] = v;
        }
      __syncthreads();
#pragma unroll
      for (int q = 0; q < 2; ++q) {
        int g = tid + q * 256;
        int b = g >> 3, colg = g & 7;
        u64 ph = 0, pl = 0;
#pragma unroll
        for (int ii = 0; ii < 4; ++ii) {
          float v = cf[b * 32 + colg * 4 + ii];
          u16 hi, lo;
          split2(v, &hi, &lo);
          ph |= (u64)hi << (16 * ii);
          pl |= (u64)lo << (16 * ii);
        }
        long o = (long)(t + 1) * 65536 + (long)b * 1024 + n0 + colg * 4;
        astore_u64(dctx_h + o, ph);
        astore_u64(dctx_l + o, pl);
      }
    }
    if (t < T_ - 1) gridbar(flags, seq);
    seq++;
  }
}

// ---------------- in-place log-softmax over V per row ----------------
__device__ __forceinline__ void lse_comb(float& m, float& s, float mo, float so) {
  float M = fmaxf(m, mo);
  s = s * __expf(m - M) + so * __expf(mo - M);
  m = M;
}

__launch_bounds__(256)
__global__ void k_lsm(float* __restrict__ dout) {
  long base = (long)blockIdx.x * V_;
  int tid = threadIdx.x;
  float m = -3.0e38f, s = 0.f;
  for (int v = tid; v < V_; v += 256) {
    float x = dout[base + v];
    if (x > m) {
      s = s * __expf(m - x) + 1.f;
      m = x;
    } else {
      s += __expf(x - m);
    }
  }
#pragma unroll
  for (int off = 32; off; off >>= 1) {
    float mo = __shfl_xor(m, off), so = __shfl_xor(s, off);
    lse_comb(m, s, mo, so);
  }
  __shared__ float ms[4], ss[4];
  if ((tid & 63) == 0) { ms[tid >> 6] = m; ss[tid >> 6] = s; }
  __syncthreads();
  float M = ms[0], S = ss[0];
  for (int w2 = 1; w2 < 4; ++w2) lse_comb(M, S, ms[w2], ss[w2]);
  float logden = M + logf(S);
  for (int v = tid; v < V_; v += 256) dout[base + v] -= logden;
}

// ---------------- host launcher ----------------
extern "C" void kernel_launch(void* const* d_in, const int* in_sizes, int n_in,
                              void* d_out, int out_size, void* d_ws, size_t ws_size,
                              hipStream_t stream) {
  (void)in_sizes; (void)n_in; (void)out_size;
  const int* input = (const int*)d_in[0];
  const float* memory = (const float*)d_in[1];
  const float* enc = (const float*)d_in[2];
  const int* xs_len = (const int*)d_in[3];
  const float* emb = (const float*)d_in[4];
  const float* wih = (const float*)d_in[5];
  const float* whh = (const float*)d_in[6];
  const float* bih = (const float*)d_in[7];
  const float* bhh = (const float*)d_in[8];
  const float* l1 = (const float*)d_in[9];
  const float* l2 = (const float*)d_in[10];
  const float* wout = (const float*)d_in[11];
  const float* bout = (const float*)d_in[12];
  float* out = (float*)d_out;
  char* w = (char*)d_ws;

  size_t off = 0;
  auto alloc = [&](size_t bytes) {
    size_t o = off;
    off = (off + bytes + 255) & ~(size_t)255;
    return o;
  };
  const size_t N_WIH = 3072UL * 2048, N_WHH = 3072UL * 1024, N_L2 = 1024UL * 2048;
  const size_t N_L1 = 1024UL * 1024, N_ENC = 4096UL * 1024, N_WOUT = 32000UL * 1024;
  const size_t N_EMBX = 2048UL * 1024, N_ENCT = 4096UL * 1024;
  const size_t N_EMBI = 2048UL * 3072, N_ROT = 33UL * 65536;

  size_t o_wih_h = alloc(2 * N_WIH), o_wih_l = alloc(2 * N_WIH);
  size_t o_whh_h = alloc(2 * N_WHH), o_whh_l = alloc(2 * N_WHH);
  size_t o_l2_h = alloc(2 * N_L2), o_l2_l = alloc(2 * N_L2);
  size_t o_l1t_h = alloc(2 * N_L1), o_l1t_l = alloc(2 * N_L1);
  size_t o_ctx_h = alloc(2 * N_ROT), o_ctx_l = alloc(2 * N_ROT);
  size_t o_hh = alloc(2 * N_ROT), o_hl = alloc(2 * N_ROT);
  size_t o_gip = alloc(4 * 2 * 196608), o_ghp = alloc(4 * 2 * 196608);
  size_t o_actx = alloc(4 * 65536);
  size_t o_bar = alloc(16384);
  size_t o_arena = alloc(2 * N_ENC * 2 + 2 * N_EMBX * 2 + 4 * N_EMBI + 4 * N_ENCT * 2);

  if (off > ws_size) {
    k_guard<<<1, 1, 0, stream>>>(out, 1.0e8f + (float)(ws_size >> 20));
    return;
  }

  u16* wih_h = (u16*)(w + o_wih_h);   u16* wih_l = (u16*)(w + o_wih_l);
  u16* whh_h = (u16*)(w + o_whh_h);   u16* whh_l = (u16*)(w + o_whh_l);
  u16* l2_h = (u16*)(w + o_l2_h);     u16* l2_l = (u16*)(w + o_l2_l);
  u16* l1t_h = (u16*)(w + o_l1t_h);   u16* l1t_l = (u16*)(w + o_l1t_l);
  u16* ctx_h = (u16*)(w + o_ctx_h);   u16* ctx_l = (u16*)(w + o_ctx_l);
  u16* hh_r = (u16*)(w + o_hh);       u16* hl_r = (u16*)(w + o_hl);
  float* gip = (float*)(w + o_gip);
  float* ghp = (float*)(w + o_ghp);
  float* actx = (float*)(w + o_actx);
  unsigned* flags = (unsigned*)(w + o_bar);

  char* ar = w + o_arena;
  u16* enc_h = (u16*)ar;
  u16* enc_l = (u16*)(ar + 2 * N_ENC);
  u16* embx_h = (u16*)(ar + 4 * N_ENC);
  u16* embx_l = (u16*)(ar + 4 * N_ENC + 2 * N_EMBX);
  float* embi = (float*)(ar + 4 * N_ENC + 4 * N_EMBX);
  float* encT = (float*)(ar + 4 * N_ENC + 4 * N_EMBX + 4 * N_EMBI);
  float* encL = (float*)(ar + 4 * N_ENC + 4 * N_EMBX + 4 * N_EMBI + 4 * N_ENCT);
  u16* wout_b = (u16*)ar;  // overlays prep arena after k_rec

  // allow 152 KB dynamic LDS for k_rec (host-side, graph-capture safe)
  hipFuncSetAttribute((const void*)k_rec, hipFuncAttributeMaxDynamicSharedMemorySize,
                      LDS_BYTES);

  // prep
  k_split<<<2048, 256, 0, stream>>>(wih, wih_h, wih_l, (int)N_WIH);
  k_split<<<2048, 256, 0, stream>>>(whh, whh_h, whh_l, (int)N_WHH);
  k_split<<<2048, 256, 0, stream>>>(l2, l2_h, l2_l, (int)N_L2);
  k_split<<<2048, 256, 0, stream>>>(enc, enc_h, enc_l, (int)N_ENC);
  k_l1t<<<256, 256, 0, stream>>>(l1, l1t_h, l1t_l);
  k_embx<<<2048, 256, 0, stream>>>(input, emb, embx_h, embx_l);
  k_h0<<<256, 256, 0, stream>>>(memory, hh_r, hl_r);
  hipMemsetAsync(ctx_h, 0, 131072, stream);  // dctx slot 0 = zeros
  hipMemsetAsync(ctx_l, 0, 131072, stream);
  hipMemsetAsync(flags, 0, 16384, stream);

  // encT = enc @ l1 ; encL = enc @ l2a^T ; embi = embx @ w_ih[:, :1024]^T
  k_gemm128<1, 0><<<256, 256, 0, stream>>>(enc_h, enc_l, l1t_h, l1t_l, encT, nullptr,
                                           32, 8, 1024, 1024, 1024, 1024);
  k_gemm128<1, 0><<<256, 256, 0, stream>>>(enc_h, enc_l, l2_h, l2_l, encL, nullptr,
                                           32, 8, 1024, 1024, 2048, 1024);
  k_gemm128<1, 0><<<384, 256, 0, stream>>>(embx_h, embx_l, wih_h, wih_l, embi, nullptr,
                                           16, 24, 1024, 1024, 2048, 3072);

  // persistent recurrence (224 blocks, LDS-resident weights)
  k_rec<<<NB_, 256, LDS_BYTES, stream>>>(embi, ctx_h, ctx_l, hh_r, hl_r, memory,
                                         wih_h, wih_l, whh_h, whh_l, l2_h, l2_l,
                                         gip, ghp, actx, encT, encL, xs_len,
                                         bih, bhh, out, flags);

  // wout -> bf16 (overlays dead prep arena)
  k_tobf<<<4096, 256, 0, stream>>>(wout, wout_b, (int)N_WOUT);

  // logits = dctx_all @ w_out^T + b_out, scattered to [b][t][v]
  k_gemm128<0, 1><<<4000, 256, 0, stream>>>(ctx_h + 65536, nullptr, wout_b, nullptr,
                                            out, bout, 16, 250, 1024, 1024, 1024, 0);
  // in-place log-softmax per (b,t) row
  k_lsm<<<2048, 256, 0, stream>>>(out);
}

// Round 7
// 1999.893 us; speedup vs baseline: 1.4960x; 1.3805x over previous
//
#include <hip/hip_runtime.h>

// ---------------------------------------------------------------------------
// AttentionDecoder: B=64 T=32 S=64 H=1024 V=32000
// R7: R6 structure (LDS-resident weights, Ph2 spread over 256 blocks) with
//     encT/encL reverted to f32 (R6's fp16 broke correctness: 30x rel-err
//     recirculated through the 32-step recurrence -> absmax 1.44).
//  - Ph1(192 blk): gi=ctx@wih2^T, gh=h@whh^T from LDS-resident weights
//  - Ph2a(256 blk): GRU quarter + partial scores (f32 encT) -> psc
//  - Ph2c(256 blk): redundant softmax + partial ctx (f32 encL) -> ctxp
//  - Ph3(32 blk): dctx[t+1] = tanh(sum ctxp + h@l2b^T)
//  - 4 grid barriers/step. Coherence: atomic producers, cached consumers on
//    rotation-fresh buffers (proven R4/R5).
// ---------------------------------------------------------------------------

#define B_ 64
#define T_ 32
#define S_ 64
#define H_ 1024
#define V_ 32000
#define NB_ 256
#define LDS_BYTES 152064
// LDS: [0,65536) W_HI | [65536,131072) W_LO | [131072,147456) A_HI/A_LO
//      [147456,148480) hq f32[256] | [148480,148736) at_s f32[64]
//      Ph3 reuses [131072,139264) as f32 C-tile

#define HID_OFF 65536000L
#define ATT_OFF 65601536L
#define CTF_OFF 65732608L

typedef __attribute__((ext_vector_type(8))) short bf16x8;
typedef __attribute__((ext_vector_type(4))) float f32x4;
typedef __attribute__((ext_vector_type(4))) unsigned int u32x4;
typedef unsigned short u16;
typedef unsigned long long u64;

__device__ __forceinline__ u16 f2bf(float v) {
  unsigned int u = __float_as_uint(v);
  unsigned int r = (u + 0x7fffu + ((u >> 16) & 1u)) >> 16;  // RNE
  return (u16)r;
}
__device__ __forceinline__ float bf2f(u16 h) {
  return __uint_as_float(((unsigned int)h) << 16);
}
__device__ __forceinline__ void split2(float v, u16* hi, u16* lo) {
  u16 h = f2bf(v);
  *hi = h;
  *lo = f2bf(v - bf2f(h));
}

// ---- coherent-path (agent-scope relaxed atomic) helpers ----
__device__ __forceinline__ u64 aload_u64(const void* p) {
  return __hip_atomic_load((const u64*)p, __ATOMIC_RELAXED, __HIP_MEMORY_SCOPE_AGENT);
}
__device__ __forceinline__ unsigned aload_u32(const void* p) {
  return __hip_atomic_load((const unsigned*)p, __ATOMIC_RELAXED, __HIP_MEMORY_SCOPE_AGENT);
}
__device__ __forceinline__ void astore_u64(void* p, u64 v) {
  __hip_atomic_store((u64*)p, v, __ATOMIC_RELAXED, __HIP_MEMORY_SCOPE_AGENT);
}
__device__ __forceinline__ void astore_f32(float* p, float v) {
  __hip_atomic_store((unsigned*)p, __float_as_uint(v), __ATOMIC_RELAXED,
                     __HIP_MEMORY_SCOPE_AGENT);
}

// ---------------- conversion / prep kernels ----------------

__global__ void k_split(const float* __restrict__ src, u16* __restrict__ hi,
                        u16* __restrict__ lo, int n) {
  int i = blockIdx.x * blockDim.x + threadIdx.x;
  int stride = gridDim.x * blockDim.x;
  for (; i < n; i += stride) split2(src[i], &hi[i], &lo[i]);
}

__global__ void k_tobf(const float* __restrict__ src, u16* __restrict__ dst, int n) {
  int i = blockIdx.x * blockDim.x + threadIdx.x;
  int stride = gridDim.x * blockDim.x;
  for (; i < n; i += stride) dst[i] = f2bf(src[i]);
}

// l1 (H,H) row-major [i][k] -> l1T hi/lo [k][i]
__global__ void k_l1t(const float* __restrict__ l1, u16* __restrict__ hi,
                      u16* __restrict__ lo) {
  __shared__ float tile[64][65];
  int it = blockIdx.x & 15, kt = blockIdx.x >> 4;
  for (int q = 0; q < 16; ++q) {
    int idx = q * 256 + threadIdx.x;
    int r = idx >> 6, c = idx & 63;
    tile[r][c] = l1[(long)(it * 64 + r) * H_ + kt * 64 + c];
  }
  __syncthreads();
  for (int q = 0; q < 16; ++q) {
    int idx = q * 256 + threadIdx.x;
    int r = idx >> 6, c = idx & 63;
    long o = (long)(kt * 64 + r) * H_ + it * 64 + c;
    split2(tile[c][r], &hi[o], &lo[o]);
  }
}

// gather embeddings: embx[t][b][k] hi/lo
__global__ void k_embx(const int* __restrict__ inp, const float* __restrict__ emb,
                       u16* __restrict__ hi, u16* __restrict__ lo) {
  int bt = blockIdx.x;
  int b = bt >> 5, t = bt & 31;
  int id = inp[b * T_ + t];
  const float* src = emb + (long)id * H_;
  long base = (long)(t * B_ + b) * H_;
  for (int k = threadIdx.x; k < H_; k += 256) split2(src[k], &hi[base + k], &lo[base + k]);
}

// h0 -> hh_r/hl_r slot 0
__global__ void k_h0(const float* __restrict__ mem, u16* __restrict__ hh,
                     u16* __restrict__ hl) {
  int i = blockIdx.x * 256 + threadIdx.x;  // 65536
  float v = mem[i];
  split2(v, &hh[i], &hl[i]);
}

__global__ void k_guard(float* out, float v) {
  if (blockIdx.x == 0 && threadIdx.x == 0) out[0] = v;
}

// ---------------- 128x128 tile GEMM (BK=32), optional split-bf16 ----------------
template <int SPLIT, int OMODE>
__launch_bounds__(256)
__global__ void k_gemm128(const u16* __restrict__ Ah, const u16* __restrict__ Al,
                          const u16* __restrict__ Bh, const u16* __restrict__ Bl,
                          float* __restrict__ C, const float* __restrict__ bias,
                          int Mtiles, int Ntiles, int K, int Arow, int Brow, int Crow) {
  (void)Ntiles;
  int bx = blockIdx.x;
  int mt = bx % Mtiles, nt = bx / Mtiles;
  int m0 = mt * 128, n0 = nt * 128;

  __shared__ __attribute__((aligned(16))) u16 lds[(SPLIT ? 4 : 2) * 4096];
  char* L = (char*)lds;
  const int tid = threadIdx.x;
  const int lane = tid & 63, wid = tid >> 6;
  const int wm = wid & 1, wn = wid >> 1;
  const int l15 = lane & 15, kq = lane >> 4;

  f32x4 acc[4][4];
  const f32x4 z4 = {0.f, 0.f, 0.f, 0.f};
#pragma unroll
  for (int i = 0; i < 4; ++i)
#pragma unroll
    for (int j = 0; j < 4; ++j) acc[i][j] = z4;

  const int ksteps = K >> 5;
  for (int kt = 0; kt < ksteps; ++kt) {
    __syncthreads();
#pragma unroll
    for (int h2 = 0; h2 < 2; ++h2) {
      int r = (tid >> 2) + (h2 << 6);
      int slot = tid & 3;
      int so = ((slot ^ (r & 3)) << 4);
      long ga = (long)(m0 + r) * Arow + (kt << 5) + (slot << 3);
      long gb = (long)(n0 + r) * Brow + (kt << 5) + (slot << 3);
      *(u32x4*)(L + r * 64 + so) = *(const u32x4*)(Ah + ga);
      *(u32x4*)(L + 8192 + r * 64 + so) = *(const u32x4*)(Bh + gb);
      if (SPLIT) {
        *(u32x4*)(L + 16384 + r * 64 + so) = *(const u32x4*)(Al + ga);
        *(u32x4*)(L + 24576 + r * 64 + so) = *(const u32x4*)(Bl + gb);
      }
    }
    __syncthreads();
    bf16x8 aH[4], bH[4], aL[4], bL[4];
#pragma unroll
    for (int mi = 0; mi < 4; ++mi) {
      int r = (wm << 6) + (mi << 4) + l15;
      int off = r * 64 + ((kq ^ (r & 3)) << 4);
      aH[mi] = *(const bf16x8*)(L + off);
      if (SPLIT) aL[mi] = *(const bf16x8*)(L + 16384 + off);
    }
#pragma unroll
    for (int ni = 0; ni < 4; ++ni) {
      int c = (wn << 6) + (ni << 4) + l15;
      int off = c * 64 + ((kq ^ (c & 3)) << 4);
      bH[ni] = *(const bf16x8*)(L + 8192 + off);
      if (SPLIT) bL[ni] = *(const bf16x8*)(L + 24576 + off);
    }
#pragma unroll
    for (int mi = 0; mi < 4; ++mi)
#pragma unroll
      for (int ni = 0; ni < 4; ++ni) {
        acc[mi][ni] = __builtin_amdgcn_mfma_f32_16x16x32_bf16(aH[mi], bH[ni], acc[mi][ni], 0, 0, 0);
        if (SPLIT) {
          acc[mi][ni] = __builtin_amdgcn_mfma_f32_16x16x32_bf16(aL[mi], bH[ni], acc[mi][ni], 0, 0, 0);
          acc[mi][ni] = __builtin_amdgcn_mfma_f32_16x16x32_bf16(aH[mi], bL[ni], acc[mi][ni], 0, 0, 0);
        }
      }
  }
#pragma unroll
  for (int mi = 0; mi < 4; ++mi)
#pragma unroll
    for (int ni = 0; ni < 4; ++ni)
#pragma unroll
      for (int e = 0; e < 4; ++e) {
        int r = (wm << 6) + (mi << 4) + (kq << 2) + e;
        int c = (wn << 6) + (ni << 4) + l15;
        int gm = m0 + r, gn = n0 + c;
        float v = acc[mi][ni][e];
        if (OMODE == 0) {
          C[(long)gm * Crow + gn] = v;
        } else {
          v += bias[gn];
          C[((long)(gm & 63) * T_ + (gm >> 6)) * V_ + gn] = v;
        }
      }
}

// ---------------- grid barrier: release flag + distributed relaxed poll ----
__device__ __forceinline__ void gridbar(unsigned* flags, unsigned seq) {
  __syncthreads();
  if (threadIdx.x == 0)
    __hip_atomic_store(flags + blockIdx.x * 16, seq, __ATOMIC_RELEASE,
                       __HIP_MEMORY_SCOPE_AGENT);
  if (threadIdx.x < 64) {
    int l = threadIdx.x;
    for (;;) {
      unsigned a = __hip_atomic_load(flags + l * 16, __ATOMIC_RELAXED, __HIP_MEMORY_SCOPE_AGENT);
      unsigned b = __hip_atomic_load(flags + (l + 64) * 16, __ATOMIC_RELAXED, __HIP_MEMORY_SCOPE_AGENT);
      unsigned c = __hip_atomic_load(flags + (l + 128) * 16, __ATOMIC_RELAXED, __HIP_MEMORY_SCOPE_AGENT);
      unsigned d = __hip_atomic_load(flags + (l + 192) * 16, __ATOMIC_RELAXED, __HIP_MEMORY_SCOPE_AGENT);
      if (__all((a >= seq) & (b >= seq) & (c >= seq) & (d >= seq))) break;
      __builtin_amdgcn_s_sleep(1);
    }
  }
  __syncthreads();
}

// ---------------- persistent recurrence kernel ----------------
__launch_bounds__(256)
__global__ void k_rec(const float* __restrict__ embi,
                      u16* __restrict__ dctx_h, u16* __restrict__ dctx_l,
                      u16* __restrict__ hh_r, u16* __restrict__ hl_r,
                      const float* __restrict__ memory,
                      const u16* __restrict__ wih_h, const u16* __restrict__ wih_l,
                      const u16* __restrict__ whh_h, const u16* __restrict__ whh_l,
                      const u16* __restrict__ l2_h, const u16* __restrict__ l2_l,
                      float* __restrict__ gip, float* __restrict__ ghp,
                      float* __restrict__ psc, float* __restrict__ ctxp,
                      const float* __restrict__ encT, const float* __restrict__ encL,
                      const int* __restrict__ xs_len,
                      const float* __restrict__ bih, const float* __restrict__ bhh,
                      float* __restrict__ dout, unsigned* flags) {
  extern __shared__ __attribute__((aligned(16))) char L[];
  char* W_HI = L;
  char* W_LO = L + 65536;
  char* A_HI = L + 131072;
  char* A_LO = L + 139264;
  float* hq = (float*)(L + 147456);
  float* at_s = (float*)(L + 148480);
  const int bx = blockIdx.x;
  const int tid = threadIdx.x;
  const int lane = tid & 63, wid = tid >> 6;
  const int wm = wid & 1, wn = wid >> 1;
  const int l15 = lane & 15, kq = lane >> 4;
  const f32x4 z4 = {0.f, 0.f, 0.f, 0.f};
  unsigned seq = 1;

  // ---- role decode ----
  const int isGI = (bx < 96);
  const int isGH = (bx >= 96 && bx < 192);
  const int isL2 = (bx >= 192 && bx < 224);
  const int sb = bx >> 2;        // Ph2 batch
  const int sq = bx & 3;         // Ph2 quarter
  int nt = 0, kc = 0, n0 = 0;
  const u16 *Wg_h = nullptr, *Wg_l = nullptr;
  int wrs = 0;
  if (isGI) {
    nt = bx % 48; kc = bx / 48;
    Wg_h = wih_h + 1024 + (long)nt * 64 * 2048 + kc * 512;
    Wg_l = wih_l + 1024 + (long)nt * 64 * 2048 + kc * 512;
    wrs = 2048;
  } else if (isGH) {
    int j2 = bx - 96;
    nt = j2 % 48; kc = j2 / 48;
    Wg_h = whh_h + (long)nt * 64 * 1024 + kc * 512;
    Wg_l = whh_l + (long)nt * 64 * 1024 + kc * 512;
    wrs = 1024;
  } else if (isL2) {
    n0 = (bx - 192) << 5;
    Wg_h = l2_h + 1024 + (long)n0 * 2048;
    Wg_l = l2_l + 1024 + (long)n0 * 2048;
    wrs = 2048;
  }

  // ---- one-time: load weight slab into LDS ----
  if (isGI || isGH) {
    for (int e = tid; e < 4096; e += 256) {
      int st = e >> 8, r = (e >> 2) & 63, slot = e & 3;
      long g = (long)r * wrs + st * 32 + slot * 8;
      int o = st * 4096 + r * 64 + ((slot ^ (r & 3)) << 4);
      *(u32x4*)(W_HI + o) = *(const u32x4*)(Wg_h + g);
      *(u32x4*)(W_LO + o) = *(const u32x4*)(Wg_l + g);
    }
  } else if (isL2) {
    for (int e = tid; e < 4096; e += 256) {
      int st = e >> 7, r = (e >> 2) & 31, slot = e & 3;
      long g = (long)r * wrs + st * 32 + slot * 8;
      int o = st * 2048 + r * 64 + ((slot ^ (r & 3)) << 4);
      *(u32x4*)(W_HI + o) = *(const u32x4*)(Wg_h + g);
      *(u32x4*)(W_LO + o) = *(const u32x4*)(Wg_l + g);
    }
  }
  __syncthreads();

  // h_prev element owned by this thread: h[sb][sq*256 + tid]
  float hpv = memory[sb * 1024 + sq * 256 + tid];

  // A-staging thread constants
  const int pr = tid >> 2, ps = tid & 3;
  const int ao = pr * 64 + ((ps ^ (pr & 3)) << 4);

  for (int t = 0; t < T_; ++t) {
    // ================= Ph1: gates GEMMs (blocks 0..191) =================
    if (isGI || isGH) {
      const u16* Ah;
      const u16* Al;
      float* outp;
      if (isGI) {
        Ah = dctx_h + (long)t * 65536 + kc * 512;   // rotation-fresh
        Al = dctx_l + (long)t * 65536 + kc * 512;
        outp = gip + (long)kc * 196608 + nt * 64;
      } else {
        Ah = hh_r + (long)t * 65536 + kc * 512;
        Al = hl_r + (long)t * 65536 + kc * 512;
        outp = ghp + (long)kc * 196608 + nt * 64;
      }
      const long g0 = (long)pr * 1024 + ps * 8;
      u32x4 ph0 = *(const u32x4*)(Ah + g0);
      u32x4 ph1 = *(const u32x4*)(Ah + g0 + 32);
      u32x4 pl0 = *(const u32x4*)(Al + g0);
      u32x4 pl1 = *(const u32x4*)(Al + g0 + 32);

      f32x4 acc[2][2];
#pragma unroll
      for (int i = 0; i < 2; ++i)
#pragma unroll
        for (int j = 0; j < 2; ++j) acc[i][j] = z4;

      for (int kt = 0; kt < 8; ++kt) {
        __syncthreads();
        *(u32x4*)(A_HI + ao) = ph0;
        *(u32x4*)(A_HI + 4096 + ao) = ph1;
        *(u32x4*)(A_LO + ao) = pl0;
        *(u32x4*)(A_LO + 4096 + ao) = pl1;
        __syncthreads();
        if (kt < 7) {
          long g = g0 + (kt + 1) * 64;
          ph0 = *(const u32x4*)(Ah + g);
          ph1 = *(const u32x4*)(Ah + g + 32);
          pl0 = *(const u32x4*)(Al + g);
          pl1 = *(const u32x4*)(Al + g + 32);
        }
#pragma unroll
        for (int sub = 0; sub < 2; ++sub) {
          const int stw = (kt * 2 + sub) * 4096;
          const int sta = sub * 4096;
          bf16x8 aH[2], aL[2], bH[2], bL[2];
#pragma unroll
          for (int mi = 0; mi < 2; ++mi) {
            int rr = (wm << 5) + (mi << 4) + l15;
            int off = rr * 64 + ((kq ^ (rr & 3)) << 4);
            aH[mi] = *(const bf16x8*)(A_HI + sta + off);
            aL[mi] = *(const bf16x8*)(A_LO + sta + off);
          }
#pragma unroll
          for (int ni = 0; ni < 2; ++ni) {
            int c = (wn << 5) + (ni << 4) + l15;
            int off = c * 64 + ((kq ^ (c & 3)) << 4);
            bH[ni] = *(const bf16x8*)(W_HI + stw + off);
            bL[ni] = *(const bf16x8*)(W_LO + stw + off);
          }
#pragma unroll
          for (int mi = 0; mi < 2; ++mi)
#pragma unroll
            for (int ni = 0; ni < 2; ++ni) {
              acc[mi][ni] = __builtin_amdgcn_mfma_f32_16x16x32_bf16(aH[mi], bH[ni], acc[mi][ni], 0, 0, 0);
              acc[mi][ni] = __builtin_amdgcn_mfma_f32_16x16x32_bf16(aL[mi], bH[ni], acc[mi][ni], 0, 0, 0);
              acc[mi][ni] = __builtin_amdgcn_mfma_f32_16x16x32_bf16(aH[mi], bL[ni], acc[mi][ni], 0, 0, 0);
            }
        }
      }
#pragma unroll
      for (int mi = 0; mi < 2; ++mi)
#pragma unroll
        for (int ni = 0; ni < 2; ++ni)
#pragma unroll
          for (int e = 0; e < 4; ++e) {
            int r = (wm << 5) + (mi << 4) + (kq << 2) + e;
            int c = (wn << 5) + (ni << 4) + l15;
            astore_f32(outp + (long)r * 3072 + c, acc[mi][ni][e]);
          }
    }
    gridbar(flags, seq++);

    // ========== Ph2a: GRU quarter + partial scores (ALL 256 blocks) ========
    {
      const int b = sb, q = sq;
      const int j = (q << 8) + tid;
      const float* eb = embi + ((long)t * 64 + b) * 3072;
      float g0r = __uint_as_float(aload_u32(gip + b * 3072 + j));
      float g1r = __uint_as_float(aload_u32(gip + 196608 + b * 3072 + j));
      float g0z = __uint_as_float(aload_u32(gip + b * 3072 + 1024 + j));
      float g1z = __uint_as_float(aload_u32(gip + 196608 + b * 3072 + 1024 + j));
      float g0n = __uint_as_float(aload_u32(gip + b * 3072 + 2048 + j));
      float g1n = __uint_as_float(aload_u32(gip + 196608 + b * 3072 + 2048 + j));
      float h0r = __uint_as_float(aload_u32(ghp + b * 3072 + j));
      float h1r = __uint_as_float(aload_u32(ghp + 196608 + b * 3072 + j));
      float h0z = __uint_as_float(aload_u32(ghp + b * 3072 + 1024 + j));
      float h1z = __uint_as_float(aload_u32(ghp + 196608 + b * 3072 + 1024 + j));
      float h0n = __uint_as_float(aload_u32(ghp + b * 3072 + 2048 + j));
      float h1n = __uint_as_float(aload_u32(ghp + 196608 + b * 3072 + 2048 + j));
      float ir = eb[j] + g0r + g1r + bih[j];
      float iz = eb[1024 + j] + g0z + g1z + bih[1024 + j];
      float in2 = eb[2048 + j] + g0n + g1n + bih[2048 + j];
      float hr = h0r + h1r + bhh[j];
      float hz = h0z + h1z + bhh[1024 + j];
      float hn = h0n + h1n + bhh[2048 + j];
      float r = 1.f / (1.f + expf(-(ir + hr)));
      float z = 1.f / (1.f + expf(-(iz + hz)));
      float n = tanhf(in2 + r * hn);
      float h = (1.f - z) * n + z * hpv;
      hpv = h;
      hq[tid] = h;
      if (t == T_ - 1) dout[HID_OFF + (long)b * 1024 + j] = h;
      __syncthreads();
      // pack h quarter -> bf16 hi/lo rotated slot (wave 0)
      if (tid < 64) {
        u64 ph = 0, pl = 0;
#pragma unroll
        for (int ii = 0; ii < 4; ++ii) {
          u16 hi, lo;
          split2(hq[tid * 4 + ii], &hi, &lo);
          ph |= (u64)hi << (16 * ii);
          pl |= (u64)lo << (16 * ii);
        }
        long o = (long)(t + 1) * 65536 + (long)b * 1024 + (q << 8) + tid * 4;
        astore_u64(hh_r + o, ph);
        astore_u64(hl_r + o, pl);
      }
      // partial scores: 4 threads per s over 64-k sub-slices (f32 encT)
      {
        int s = tid >> 2, part = tid & 3;
        const float4* ep = (const float4*)(encT + (((long)b * 64 + s) << 10) + (q << 8) + (part << 6));
        const float4* hp = (const float4*)(hq + (part << 6));
        float dot = 0.f;
#pragma unroll
        for (int kk = 0; kk < 16; ++kk) {
          float4 e = ep[kk], a = hp[kk];
          dot += e.x * a.x + e.y * a.y + e.z * a.z + e.w * a.w;
        }
        dot += __shfl_xor(dot, 1);
        dot += __shfl_xor(dot, 2);
        if (part == 0) astore_f32(psc + (((b << 2) + q) << 6) + s, dot);
      }
    }
    gridbar(flags, seq++);

    // ========== Ph2c: softmax (redundant) + partial ctx (ALL blocks) =======
    {
      const int b = sb, q = sq;
      if (tid < 64) {
        int s = tid;
        float v = 0.f;
#pragma unroll
        for (int qq = 0; qq < 4; ++qq)
          v += __uint_as_float(aload_u32(psc + (((b << 2) + qq) << 6) + s));
        int len = xs_len[b];
        if (s >= len || v == 0.0f) v = -1e10f;
        float m = v;
#pragma unroll
        for (int off = 32; off; off >>= 1) m = fmaxf(m, __shfl_xor(m, off));
        float p = expf(v - m);
        float sum = p;
#pragma unroll
        for (int off = 32; off; off >>= 1) sum += __shfl_xor(sum, off);
        float a = p / sum;
        at_s[s] = a;
        if (q == 0) dout[ATT_OFF + ((long)b * T_ + t) * S_ + s] = a;
      }
      __syncthreads();
      // partial ctx over s in [16q, 16q+16)  (f32 encL)
      {
        const float* lp = encL + (((long)b * 64 + (q << 4)) << 10) + tid * 4;
        float c0 = 0.f, c1 = 0.f, c2 = 0.f, c3 = 0.f;
#pragma unroll
        for (int s2 = 0; s2 < 16; ++s2) {
          float a = at_s[(q << 4) + s2];
          float4 e = *(const float4*)(lp + (s2 << 10));
          c0 += a * e.x; c1 += a * e.y; c2 += a * e.z; c3 += a * e.w;
        }
        u64 w0 = ((u64)__float_as_uint(c1) << 32) | __float_as_uint(c0);
        u64 w1 = ((u64)__float_as_uint(c3) << 32) | __float_as_uint(c2);
        long o = (((long)(b << 2) + q) << 10) + tid * 4;
        astore_u64(ctxp + o, w0);
        astore_u64(ctxp + o + 2, w1);
      }
    }
    gridbar(flags, seq++);

    // ========== Ph3: dctx[t+1] = tanh(Σq ctxp + h@l2b^T) (blocks 192..223) ==
    if (isL2) {
      const u16* Ah = hh_r + (long)(t + 1) * 65536;   // rotation-fresh
      const u16* Al = hl_r + (long)(t + 1) * 65536;
      const long g0 = (long)pr * 1024 + ps * 8;
      u32x4 ph0 = *(const u32x4*)(Ah + g0);
      u32x4 ph1 = *(const u32x4*)(Ah + g0 + 32);
      u32x4 pl0 = *(const u32x4*)(Al + g0);
      u32x4 pl1 = *(const u32x4*)(Al + g0 + 32);

      f32x4 acc[2];
      acc[0] = z4; acc[1] = z4;
      for (int kt = 0; kt < 16; ++kt) {
        __syncthreads();
        *(u32x4*)(A_HI + ao) = ph0;
        *(u32x4*)(A_HI + 4096 + ao) = ph1;
        *(u32x4*)(A_LO + ao) = pl0;
        *(u32x4*)(A_LO + 4096 + ao) = pl1;
        __syncthreads();
        if (kt < 15) {
          long g = g0 + (kt + 1) * 64;
          ph0 = *(const u32x4*)(Ah + g);
          ph1 = *(const u32x4*)(Ah + g + 32);
          pl0 = *(const u32x4*)(Al + g);
          pl1 = *(const u32x4*)(Al + g + 32);
        }
#pragma unroll
        for (int sub = 0; sub < 2; ++sub) {
          const int stw = (kt * 2 + sub) * 2048;
          const int sta = sub * 4096;
          bf16x8 aH[2], aL[2], bH, bL;
#pragma unroll
          for (int mi = 0; mi < 2; ++mi) {
            int rr = (wm << 5) + (mi << 4) + l15;
            int off = rr * 64 + ((kq ^ (rr & 3)) << 4);
            aH[mi] = *(const bf16x8*)(A_HI + sta + off);
            aL[mi] = *(const bf16x8*)(A_LO + sta + off);
          }
          {
            int c = (wn << 4) + l15;
            int off = c * 64 + ((kq ^ (c & 3)) << 4);
            bH = *(const bf16x8*)(W_HI + stw + off);
            bL = *(const bf16x8*)(W_LO + stw + off);
          }
#pragma unroll
          for (int mi = 0; mi < 2; ++mi) {
            acc[mi] = __builtin_amdgcn_mfma_f32_16x16x32_bf16(aH[mi], bH, acc[mi], 0, 0, 0);
            acc[mi] = __builtin_amdgcn_mfma_f32_16x16x32_bf16(aL[mi], bH, acc[mi], 0, 0, 0);
            acc[mi] = __builtin_amdgcn_mfma_f32_16x16x32_bf16(aH[mi], bL, acc[mi], 0, 0, 0);
          }
        }
      }
      __syncthreads();
      float* cf = (float*)(L + 131072);  // 64x32 f32 = 8 KB
#pragma unroll
      for (int mi = 0; mi < 2; ++mi)
#pragma unroll
        for (int e = 0; e < 4; ++e) {
          int rr = (wm << 5) + (mi << 4) + (kq << 2) + e;
          int cc = (wn << 4) + l15;
          float a = 0.f;
#pragma unroll
          for (int qq = 0; qq < 4; ++qq)
            a += __uint_as_float(aload_u32(ctxp + (((long)(rr << 2) + qq) << 10) + n0 + cc));
          float v = tanhf(acc[mi][e] + a);
          if (t == T_ - 1) dout[CTF_OFF + (long)rr * 1024 + n0 + cc] = v;
          cf[rr * 32 + cc] = v;
        }
      __syncthreads();
#pragma unroll
      for (int qq2 = 0; qq2 < 2; ++qq2) {
        int g = tid + qq2 * 256;
        int b = g >> 3, colg = g & 7;
        u64 ph = 0, pl = 0;
#pragma unroll
        for (int ii = 0; ii < 4; ++ii) {
          float v = cf[b * 32 + colg * 4 + ii];
          u16 hi, lo;
          split2(v, &hi, &lo);
          ph |= (u64)hi << (16 * ii);
          pl |= (u64)lo << (16 * ii);
        }
        long o = (long)(t + 1) * 65536 + (long)b * 1024 + n0 + colg * 4;
        astore_u64(dctx_h + o, ph);
        astore_u64(dctx_l + o, pl);
      }
    }
    if (t < T_ - 1) gridbar(flags, seq);
    seq++;
  }
}

// ---------------- in-place log-softmax over V per row ----------------
__device__ __forceinline__ void lse_comb(float& m, float& s, float mo, float so) {
  float M = fmaxf(m, mo);
  s = s * __expf(m - M) + so * __expf(mo - M);
  m = M;
}

__launch_bounds__(256)
__global__ void k_lsm(float* __restrict__ dout) {
  long base = (long)blockIdx.x * V_;
  int tid = threadIdx.x;
  float m = -3.0e38f, s = 0.f;
  for (int v = tid; v < V_; v += 256) {
    float x = dout[base + v];
    if (x > m) {
      s = s * __expf(m - x) + 1.f;
      m = x;
    } else {
      s += __expf(x - m);
    }
  }
#pragma unroll
  for (int off = 32; off; off >>= 1) {
    float mo = __shfl_xor(m, off), so = __shfl_xor(s, off);
    lse_comb(m, s, mo, so);
  }
  __shared__ float ms[4], ss[4];
  if ((tid & 63) == 0) { ms[tid >> 6] = m; ss[tid >> 6] = s; }
  __syncthreads();
  float M = ms[0], S = ss[0];
  for (int w2 = 1; w2 < 4; ++w2) lse_comb(M, S, ms[w2], ss[w2]);
  float logden = M + logf(S);
  for (int v = tid; v < V_; v += 256) dout[base + v] -= logden;
}

// ---------------- host launcher ----------------
extern "C" void kernel_launch(void* const* d_in, const int* in_sizes, int n_in,
                              void* d_out, int out_size, void* d_ws, size_t ws_size,
                              hipStream_t stream) {
  (void)in_sizes; (void)n_in; (void)out_size;
  const int* input = (const int*)d_in[0];
  const float* memory = (const float*)d_in[1];
  const float* enc = (const float*)d_in[2];
  const int* xs_len = (const int*)d_in[3];
  const float* emb = (const float*)d_in[4];
  const float* wih = (const float*)d_in[5];
  const float* whh = (const float*)d_in[6];
  const float* bih = (const float*)d_in[7];
  const float* bhh = (const float*)d_in[8];
  const float* l1 = (const float*)d_in[9];
  const float* l2 = (const float*)d_in[10];
  const float* wout = (const float*)d_in[11];
  const float* bout = (const float*)d_in[12];
  float* out = (float*)d_out;
  char* w = (char*)d_ws;

  size_t off = 0;
  auto alloc = [&](size_t bytes) {
    size_t o = off;
    off = (off + bytes + 255) & ~(size_t)255;
    return o;
  };
  const size_t N_WIH = 3072UL * 2048, N_WHH = 3072UL * 1024, N_L2 = 1024UL * 2048;
  const size_t N_L1 = 1024UL * 1024, N_ENC = 4096UL * 1024, N_WOUT = 32000UL * 1024;
  const size_t N_EMBX = 2048UL * 1024, N_ENCT = 4096UL * 1024;
  const size_t N_EMBI = 2048UL * 3072, N_ROT = 33UL * 65536;

  size_t o_wih_h = alloc(2 * N_WIH), o_wih_l = alloc(2 * N_WIH);
  size_t o_whh_h = alloc(2 * N_WHH), o_whh_l = alloc(2 * N_WHH);
  size_t o_l2_h = alloc(2 * N_L2), o_l2_l = alloc(2 * N_L2);
  size_t o_l1t_h = alloc(2 * N_L1), o_l1t_l = alloc(2 * N_L1);
  size_t o_ctx_h = alloc(2 * N_ROT), o_ctx_l = alloc(2 * N_ROT);
  size_t o_hh = alloc(2 * N_ROT), o_hl = alloc(2 * N_ROT);
  size_t o_gip = alloc(4 * 2 * 196608), o_ghp = alloc(4 * 2 * 196608);
  size_t o_psc = alloc(4 * 16384);
  size_t o_ctxp = alloc(4 * 262144);
  size_t o_bar = alloc(16384);
  // arena: prep-only buffers; wout_b (64 MB) overlays the FRONT after k_rec.
  // encT/encL (f32, read during k_rec) sit at the arena TAIL (offset 50.4 MB+),
  // overwritten only by nothing: wout_b covers [0, 64 MB) which includes encT
  // start (50.4 MB) -- but k_tobf runs AFTER k_rec completes (stream order),
  // and encT/encL are dead once k_rec retires. Same scheme as R5 (passed).
  size_t o_arena = alloc(2 * N_ENC * 2 + 2 * N_EMBX * 2 + 4 * N_EMBI + 4 * N_ENCT * 2);

  if (off > ws_size) {
    k_guard<<<1, 1, 0, stream>>>(out, 1.0e8f + (float)(ws_size >> 20));
    return;
  }

  u16* wih_h = (u16*)(w + o_wih_h);   u16* wih_l = (u16*)(w + o_wih_l);
  u16* whh_h = (u16*)(w + o_whh_h);   u16* whh_l = (u16*)(w + o_whh_l);
  u16* l2_h = (u16*)(w + o_l2_h);     u16* l2_l = (u16*)(w + o_l2_l);
  u16* l1t_h = (u16*)(w + o_l1t_h);   u16* l1t_l = (u16*)(w + o_l1t_l);
  u16* ctx_h = (u16*)(w + o_ctx_h);   u16* ctx_l = (u16*)(w + o_ctx_l);
  u16* hh_r = (u16*)(w + o_hh);       u16* hl_r = (u16*)(w + o_hl);
  float* gip = (float*)(w + o_gip);
  float* ghp = (float*)(w + o_ghp);
  float* psc = (float*)(w + o_psc);
  float* ctxp = (float*)(w + o_ctxp);
  unsigned* flags = (unsigned*)(w + o_bar);

  char* ar = w + o_arena;
  u16* enc_h = (u16*)ar;
  u16* enc_l = (u16*)(ar + 2 * N_ENC);
  u16* embx_h = (u16*)(ar + 4 * N_ENC);
  u16* embx_l = (u16*)(ar + 4 * N_ENC + 2 * N_EMBX);
  float* embi = (float*)(ar + 4 * N_ENC + 4 * N_EMBX);
  float* encT = (float*)(ar + 4 * N_ENC + 4 * N_EMBX + 4 * N_EMBI);
  float* encL = (float*)(ar + 4 * N_ENC + 4 * N_EMBX + 4 * N_EMBI + 4 * N_ENCT);
  u16* wout_b = (u16*)ar;  // overlays prep arena after k_rec

  hipFuncSetAttribute((const void*)k_rec, hipFuncAttributeMaxDynamicSharedMemorySize,
                      LDS_BYTES);

  // prep
  k_split<<<2048, 256, 0, stream>>>(wih, wih_h, wih_l, (int)N_WIH);
  k_split<<<2048, 256, 0, stream>>>(whh, whh_h, whh_l, (int)N_WHH);
  k_split<<<2048, 256, 0, stream>>>(l2, l2_h, l2_l, (int)N_L2);
  k_split<<<2048, 256, 0, stream>>>(enc, enc_h, enc_l, (int)N_ENC);
  k_l1t<<<256, 256, 0, stream>>>(l1, l1t_h, l1t_l);
  k_embx<<<2048, 256, 0, stream>>>(input, emb, embx_h, embx_l);
  k_h0<<<256, 256, 0, stream>>>(memory, hh_r, hl_r);
  hipMemsetAsync(ctx_h, 0, 131072, stream);  // dctx slot 0 = zeros
  hipMemsetAsync(ctx_l, 0, 131072, stream);
  hipMemsetAsync(flags, 0, 16384, stream);

  // encT = enc @ l1 ; encL = enc @ l2a^T ; embi = embx @ w_ih[:, :1024]^T
  k_gemm128<1, 0><<<256, 256, 0, stream>>>(enc_h, enc_l, l1t_h, l1t_l, encT, nullptr,
                                           32, 8, 1024, 1024, 1024, 1024);
  k_gemm128<1, 0><<<256, 256, 0, stream>>>(enc_h, enc_l, l2_h, l2_l, encL, nullptr,
                                           32, 8, 1024, 1024, 2048, 1024);
  k_gemm128<1, 0><<<384, 256, 0, stream>>>(embx_h, embx_l, wih_h, wih_l, embi, nullptr,
                                           16, 24, 1024, 1024, 2048, 3072);

  // persistent recurrence (256 blocks, LDS-resident weights, spread Ph2)
  k_rec<<<NB_, 256, LDS_BYTES, stream>>>(embi, ctx_h, ctx_l, hh_r, hl_r, memory,
                                         wih_h, wih_l, whh_h, whh_l, l2_h, l2_l,
                                         gip, ghp, psc, ctxp, encT, encL,
                                         xs_len, bih, bhh, out, flags);

  // wout -> bf16 (overlays dead prep arena; runs after k_rec in stream order)
  k_tobf<<<4096, 256, 0, stream>>>(wout, wout_b, (int)N_WOUT);

  // logits = dctx_all @ w_out^T + b_out, scattered to [b][t][v]
  k_gemm128<0, 1><<<4000, 256, 0, stream>>>(ctx_h + 65536, nullptr, wout_b, nullptr,
                                            out, bout, 16, 250, 1024, 1024, 1024, 0);
  // in-place log-softmax per (b,t) row
  k_lsm<<<2048, 256, 0, stream>>>(out);
}